// Round 1
// baseline (24589.571 us; speedup 1.0000x reference)
//
#include <hip/hip_runtime.h>
#include <math.h>

constexpr int kB = 512, kENC = 64, kH = 512, kV = 42, kSEQ = 128;

// ---------------- generic SGEMM: C[M,N] = act(A[M,K] @ W[N,K]^T + bias[N]) ----
// Requires M%64==0, N%64==0, K%16==0.
template<bool RELU>
__global__ __launch_bounds__(256) void gemm_bias(const float* __restrict__ A,
    const float* __restrict__ W, const float* __restrict__ bias,
    float* __restrict__ C, int M, int N, int K)
{
  __shared__ float As[16][68];
  __shared__ float Bs[16][68];
  const int tid = threadIdx.x;
  const int n0 = blockIdx.x * 64;
  const int m0 = blockIdx.y * 64;
  const int tx = tid & 15;        // n sub-tile
  const int ty = tid >> 4;        // m sub-tile
  const int lr = tid >> 2;        // staging row 0..63
  const int lk = (tid & 3) << 2;  // staging k offset
  float acc[4][4] = {};
  for (int kc = 0; kc < K; kc += 16) {
    const float4 va = *(const float4*)(A + (size_t)(m0 + lr) * K + kc + lk);
    const float4 vb = *(const float4*)(W + (size_t)(n0 + lr) * K + kc + lk);
    __syncthreads();
    As[lk+0][lr] = va.x; As[lk+1][lr] = va.y; As[lk+2][lr] = va.z; As[lk+3][lr] = va.w;
    Bs[lk+0][lr] = vb.x; Bs[lk+1][lr] = vb.y; Bs[lk+2][lr] = vb.z; Bs[lk+3][lr] = vb.w;
    __syncthreads();
#pragma unroll
    for (int k = 0; k < 16; ++k) {
      const float4 a = *(const float4*)&As[k][ty << 2];
      const float4 b = *(const float4*)&Bs[k][tx << 2];
      const float av[4] = {a.x, a.y, a.z, a.w};
      const float bv[4] = {b.x, b.y, b.z, b.w};
#pragma unroll
      for (int i = 0; i < 4; ++i)
#pragma unroll
        for (int j = 0; j < 4; ++j) acc[i][j] = fmaf(av[i], bv[j], acc[i][j]);
    }
  }
  const int cn = n0 + (tx << 2);
  const float4 b4 = *(const float4*)&bias[cn];
  const float bvv[4] = {b4.x, b4.y, b4.z, b4.w};
#pragma unroll
  for (int i = 0; i < 4; ++i) {
    float4 o;
    float* op = &o.x;
#pragma unroll
    for (int j = 0; j < 4; ++j) {
      float v = acc[i][j] + bvv[j];
      if (RELU) v = fmaxf(v, 0.f);
      op[j] = v;
    }
    *(float4*)(C + (size_t)(m0 + (ty << 2) + i) * N + cn) = o;
  }
}

// ---------------- encoded = eps*exp(0.5*logvar)+mu; kld partial reduce -------
__global__ __launch_bounds__(256) void enc_kld(const float* __restrict__ mu,
    const float* __restrict__ lv, const float* __restrict__ eps,
    float* __restrict__ enc, float* __restrict__ kld)
{
  const int idx = blockIdx.x * 256 + threadIdx.x;   // < 512*64
  const float m = mu[idx], l = lv[idx];
  enc[idx] = eps[idx] * expf(0.5f * l) + m;
  float term = 1.0f + l - m * m - expf(l);
  __shared__ float red[256];
  red[threadIdx.x] = term;
  __syncthreads();
  for (int s = 128; s > 0; s >>= 1) {
    if (threadIdx.x < s) red[threadIdx.x] += red[threadIdx.x + s];
    __syncthreads();
  }
  if (threadIdx.x == 0) atomicAdd(kld, -0.5f * red[0] / (float)kB);
}

// ---------------- W_comb = w_ih0 @ d_fc2w; b_comb; gvec0 --------------------
__global__ __launch_bounds__(256) void prep_comb(const float* __restrict__ wih0,
    const float* __restrict__ bih0, const float* __restrict__ fc2w,
    const float* __restrict__ fc2b, float* __restrict__ Wc,
    float* __restrict__ bc, float* __restrict__ g0)
{
  const int idx = blockIdx.x * 256 + threadIdx.x;   // < 1536*512
  const int n = idx >> 9, j = idx & 511;
  float s = 0.f;
#pragma unroll
  for (int v = 0; v < kV; ++v) s = fmaf(wih0[n * kV + v], fc2w[v * kH + j], s);
  Wc[idx] = s;
  if (j == 0) {
    float sb = 0.f;
    for (int v = 0; v < kV; ++v) sb = fmaf(wih0[n * kV + v], fc2b[v], sb);
    bc[n] = bih0[n] + sb;
  }
  if (j == 1) g0[n] = wih0[n * kV + 41] + bih0[n];
}

// ---------------- fused GRU cell: 6 gate dots + gate math + h update --------
// tile 32(b) x 32(j); if gvec!=null, gi = gvec (step-0 one-hot input).
// If outp!=null (layer 1): atomic-partial out-projection epilogue.
__global__ __launch_bounds__(256) void gru_layer(
    const float* __restrict__ xin, const float* __restrict__ hprev,
    const float* __restrict__ Wg, const float* __restrict__ bg,
    const float* __restrict__ Wh, const float* __restrict__ bh,
    const float* __restrict__ gvec, float* __restrict__ hnew,
    float* __restrict__ outp, const float* __restrict__ pw,
    const float* __restrict__ pb, int t)
{
  __shared__ float xs[16][32];
  __shared__ float hs[16][32];
  __shared__ float wgs[16][96];
  __shared__ float whs[16][96];
  __shared__ float hts[32][33];
  const int tid = threadIdx.x;
  const int j0 = blockIdx.x * 32;
  const int b0 = blockIdx.y * 32;
  const int tb = tid & 15;
  const int tj = tid >> 4;
  const bool skip_gi = (gvec != nullptr);
  float agi[3][2][2] = {};
  float agh[3][2][2] = {};
  const int r  = tid >> 2;         // 0..63
  const int kq = (tid & 3) << 2;

  for (int kc = 0; kc < kH; kc += 16) {
    float4 vx, vh, vg0, vw0, vg1, vw1;
    if (!skip_gi && tid < 128)
      vx = *(const float4*)(xin + (size_t)(b0 + r) * kH + kc + kq);
    if (tid >= 128)
      vh = *(const float4*)(hprev + (size_t)(b0 + r - 32) * kH + kc + kq);
    {
      const int g = r >> 5, jj = r & 31;
      const size_t off = (size_t)((g << 9) + j0 + jj) * kH + kc + kq;
      if (!skip_gi) vg0 = *(const float4*)(Wg + off);
      vw0 = *(const float4*)(Wh + off);
    }
    if (tid < 128) {
      const int s = tid + 256, rr = s >> 2, kk = (s & 3) << 2;
      const int g = rr >> 5, jj = rr & 31;
      const size_t off = (size_t)((g << 9) + j0 + jj) * kH + kc + kk;
      if (!skip_gi) vg1 = *(const float4*)(Wg + off);
      vw1 = *(const float4*)(Wh + off);
    }
    __syncthreads();
    if (!skip_gi && tid < 128) {
      xs[kq+0][r] = vx.x; xs[kq+1][r] = vx.y; xs[kq+2][r] = vx.z; xs[kq+3][r] = vx.w;
    }
    if (tid >= 128) {
      const int rb = r - 32;
      hs[kq+0][rb] = vh.x; hs[kq+1][rb] = vh.y; hs[kq+2][rb] = vh.z; hs[kq+3][rb] = vh.w;
    }
    if (!skip_gi) { wgs[kq+0][r] = vg0.x; wgs[kq+1][r] = vg0.y; wgs[kq+2][r] = vg0.z; wgs[kq+3][r] = vg0.w; }
    whs[kq+0][r] = vw0.x; whs[kq+1][r] = vw0.y; whs[kq+2][r] = vw0.z; whs[kq+3][r] = vw0.w;
    if (tid < 128) {
      const int s = tid + 256, rr = s >> 2, kk = (s & 3) << 2;
      if (!skip_gi) { wgs[kk+0][rr] = vg1.x; wgs[kk+1][rr] = vg1.y; wgs[kk+2][rr] = vg1.z; wgs[kk+3][rr] = vg1.w; }
      whs[kk+0][rr] = vw1.x; whs[kk+1][rr] = vw1.y; whs[kk+2][rr] = vw1.z; whs[kk+3][rr] = vw1.w;
    }
    __syncthreads();
#pragma unroll
    for (int k = 0; k < 16; ++k) {
      float xv0 = 0.f, xv1 = 0.f;
      if (!skip_gi) {
        const float2 x2 = *(const float2*)&xs[k][tb << 1];
        xv0 = x2.x; xv1 = x2.y;
      }
      const float2 h2 = *(const float2*)&hs[k][tb << 1];
#pragma unroll
      for (int g = 0; g < 3; ++g) {
        const float2 wh2 = *(const float2*)&whs[k][(g << 5) + (tj << 1)];
        agh[g][0][0] = fmaf(h2.x, wh2.x, agh[g][0][0]);
        agh[g][0][1] = fmaf(h2.x, wh2.y, agh[g][0][1]);
        agh[g][1][0] = fmaf(h2.y, wh2.x, agh[g][1][0]);
        agh[g][1][1] = fmaf(h2.y, wh2.y, agh[g][1][1]);
        if (!skip_gi) {
          const float2 wg2 = *(const float2*)&wgs[k][(g << 5) + (tj << 1)];
          agi[g][0][0] = fmaf(xv0, wg2.x, agi[g][0][0]);
          agi[g][0][1] = fmaf(xv0, wg2.y, agi[g][0][1]);
          agi[g][1][0] = fmaf(xv1, wg2.x, agi[g][1][0]);
          agi[g][1][1] = fmaf(xv1, wg2.y, agi[g][1][1]);
        }
      }
    }
  }
  const float* gb = skip_gi ? gvec : bg;
#pragma unroll
  for (int bbi = 0; bbi < 2; ++bbi) {
#pragma unroll
    for (int jji = 0; jji < 2; ++jji) {
      const int j = j0 + (tj << 1) + jji;
      const int b = b0 + (tb << 1) + bbi;
      const float gir = agi[0][bbi][jji] + gb[j];
      const float giz = agi[1][bbi][jji] + gb[kH + j];
      const float gin = agi[2][bbi][jji] + gb[2 * kH + j];
      const float ghr = agh[0][bbi][jji] + bh[j];
      const float ghz = agh[1][bbi][jji] + bh[kH + j];
      const float ghn = agh[2][bbi][jji] + bh[2 * kH + j];
      const float rg = 1.f / (1.f + expf(-(gir + ghr)));
      const float zg = 1.f / (1.f + expf(-(giz + ghz)));
      const float ng = tanhf(gin + rg * ghn);
      const float hv = (1.f - zg) * ng + zg * hprev[(size_t)b * kH + j];
      hnew[(size_t)b * kH + j] = hv;
      hts[(tb << 1) + bbi][(tj << 1) + jji] = hv;
    }
  }
  if (outp) {
    __syncthreads();
    for (int idx = tid; idx < 32 * kV; idx += 256) {
      const int bb = idx / kV;
      const int v = idx - bb * kV;
      float s = 0.f;
#pragma unroll
      for (int jj = 0; jj < 32; ++jj)
        s = fmaf(hts[bb][jj], pw[(size_t)v * kH + j0 + jj], s);
      if (j0 == 0) s += pb[v];
      atomicAdd(outp + (size_t)(b0 + bb) * (kSEQ * kV) + (size_t)t * kV + v, s);
    }
  }
}

extern "C" void kernel_launch(void* const* d_in, const int* in_sizes, int n_in,
                              void* d_out, int out_size, void* d_ws, size_t ws_size,
                              hipStream_t stream) {
  const float* X    = (const float*)d_in[0];
  // d_in[1] = y (unused by reference math)
  const float* eps  = (const float*)d_in[2];
  const float* e1w  = (const float*)d_in[3];  const float* e1b  = (const float*)d_in[4];
  const float* e2w  = (const float*)d_in[5];  const float* e2b  = (const float*)d_in[6];
  const float* e3w  = (const float*)d_in[7];  const float* e3b  = (const float*)d_in[8];
  const float* e41w = (const float*)d_in[9];  const float* e41b = (const float*)d_in[10];
  const float* e42w = (const float*)d_in[11]; const float* e42b = (const float*)d_in[12];
  const float* fc1w = (const float*)d_in[13]; const float* fc1b = (const float*)d_in[14];
  const float* fc2w = (const float*)d_in[15]; const float* fc2b = (const float*)d_in[16];
  const float* wih0 = (const float*)d_in[17]; const float* bih0 = (const float*)d_in[18];
  const float* whh0 = (const float*)d_in[19]; const float* bhh0 = (const float*)d_in[20];
  const float* wih1 = (const float*)d_in[21]; const float* bih1 = (const float*)d_in[22];
  const float* whh1 = (const float*)d_in[23]; const float* bhh1 = (const float*)d_in[24];
  float* out = (float*)d_out;

  float* ws = (float*)d_ws;
  size_t o = 0;
  float* eh1 = ws + o; o += (size_t)kB * 2048;
  float* eh2 = ws + o; o += (size_t)kB * 1024;
  float* eh3 = ws + o; o += (size_t)kB * kH;
  float* mu  = ws + o; o += (size_t)kB * kENC;
  float* lv  = ws + o; o += (size_t)kB * kENC;
  float* enc = ws + o; o += (size_t)kB * kENC;
  float* Wc  = ws + o; o += (size_t)1536 * kH;
  float* bc  = ws + o; o += 1536;
  float* g0  = ws + o; o += 1536;
  float* h0s[2]; h0s[0] = ws + o; o += (size_t)kB * kH; h0s[1] = ws + o; o += (size_t)kB * kH;
  float* h1s[2]; h1s[0] = ws + o; o += (size_t)kB * kH; h1s[1] = ws + o; o += (size_t)kB * kH;

  const size_t dec_elems = (size_t)kB * kSEQ * kV;
  // zero decoded (atomic-accumulated) + kld slot; zero initial h_l1 state
  hipMemsetAsync(d_out, 0, (size_t)out_size * sizeof(float), stream);
  hipMemsetAsync(h1s[0], 0, (size_t)kB * kH * sizeof(float), stream);

  // ---- encoder ----
  gemm_bias<true ><<<dim3(32, 8), 256, 0, stream>>>(X,   e1w, e1b, eh1, kB, 2048, 4096);
  gemm_bias<true ><<<dim3(16, 8), 256, 0, stream>>>(eh1, e2w, e2b, eh2, kB, 1024, 2048);
  gemm_bias<true ><<<dim3( 8, 8), 256, 0, stream>>>(eh2, e3w, e3b, eh3, kB,  512, 1024);
  gemm_bias<false><<<dim3( 1, 8), 256, 0, stream>>>(eh3, e41w, e41b, mu, kB,   64,  512);
  gemm_bias<false><<<dim3( 1, 8), 256, 0, stream>>>(eh3, e42w, e42b, lv, kB,   64,  512);
  enc_kld<<<128, 256, 0, stream>>>(mu, lv, eps, enc, out + dec_elems);
  prep_comb<<<3072, 256, 0, stream>>>(wih0, bih0, fc2w, fc2b, Wc, bc, g0);
  gemm_bias<false><<<dim3(8, 8), 256, 0, stream>>>(enc, fc1w, fc1b, h0s[0], kB, kH, kENC);

  // ---- GRU decoder: 128 steps x (layer0, layer1+outproj) ----
  int cur = 0;
  for (int t = 0; t < kSEQ; ++t) {
    gru_layer<<<dim3(16, 16), 256, 0, stream>>>(
        h1s[cur], h0s[cur], Wc, bc, whh0, bhh0,
        (t == 0) ? g0 : nullptr, h0s[cur ^ 1],
        nullptr, nullptr, nullptr, t);
    gru_layer<<<dim3(16, 16), 256, 0, stream>>>(
        h0s[cur ^ 1], h1s[cur], wih1, bih1, whh1, bhh1,
        nullptr, h1s[cur ^ 1],
        out, fc2w, fc2b, t);
    cur ^= 1;
  }
}

// Round 2
// 24277.921 us; speedup vs baseline: 1.0128x; 1.0128x over previous
//
#include <hip/hip_runtime.h>
#include <hip/hip_cooperative_groups.h>
#include <math.h>

namespace cg = cooperative_groups;

constexpr int kB = 512, kENC = 64, kH = 512, kV = 42, kSEQ = 128;

// ---------------- generic SGEMM: C = act(A[M,K] @ W[N,K]^T + bias) ----------
// TR: write transposed C^T[n][m] (for producing hT layout).
template<bool RELU, bool TR>
__global__ __launch_bounds__(256) void gemm_bias(const float* __restrict__ A,
    const float* __restrict__ W, const float* __restrict__ bias,
    float* __restrict__ C, int M, int N, int K)
{
  __shared__ float As[16][68];
  __shared__ float Bs[16][68];
  const int tid = threadIdx.x;
  const int n0 = blockIdx.x * 64;
  const int m0 = blockIdx.y * 64;
  const int tx = tid & 15;
  const int ty = tid >> 4;
  const int lr = tid >> 2;
  const int lk = (tid & 3) << 2;
  float acc[4][4] = {};
  for (int kc = 0; kc < K; kc += 16) {
    const float4 va = *(const float4*)(A + (size_t)(m0 + lr) * K + kc + lk);
    const float4 vb = *(const float4*)(W + (size_t)(n0 + lr) * K + kc + lk);
    __syncthreads();
    As[lk+0][lr] = va.x; As[lk+1][lr] = va.y; As[lk+2][lr] = va.z; As[lk+3][lr] = va.w;
    Bs[lk+0][lr] = vb.x; Bs[lk+1][lr] = vb.y; Bs[lk+2][lr] = vb.z; Bs[lk+3][lr] = vb.w;
    __syncthreads();
#pragma unroll
    for (int k = 0; k < 16; ++k) {
      const float4 a = *(const float4*)&As[k][ty << 2];
      const float4 b = *(const float4*)&Bs[k][tx << 2];
      const float av[4] = {a.x, a.y, a.z, a.w};
      const float bv[4] = {b.x, b.y, b.z, b.w};
#pragma unroll
      for (int i = 0; i < 4; ++i)
#pragma unroll
        for (int jj = 0; jj < 4; ++jj) acc[i][jj] = fmaf(av[i], bv[jj], acc[i][jj]);
    }
  }
  const int cn = n0 + (tx << 2);
  const float4 b4 = *(const float4*)&bias[cn];
  const float bvv[4] = {b4.x, b4.y, b4.z, b4.w};
#pragma unroll
  for (int i = 0; i < 4; ++i) {
    const int m = m0 + (ty << 2) + i;
    if (TR) {
#pragma unroll
      for (int jj = 0; jj < 4; ++jj) {
        float v = acc[i][jj] + bvv[jj];
        if (RELU) v = fmaxf(v, 0.f);
        C[(size_t)(cn + jj) * M + m] = v;
      }
    } else {
      float4 o;
      float* op = &o.x;
#pragma unroll
      for (int jj = 0; jj < 4; ++jj) {
        float v = acc[i][jj] + bvv[jj];
        if (RELU) v = fmaxf(v, 0.f);
        op[jj] = v;
      }
      *(float4*)(C + (size_t)m * N + cn) = o;
    }
  }
}

// ---------------- encoded = eps*exp(0.5*logvar)+mu; kld partial reduce -------
__global__ __launch_bounds__(256) void enc_kld(const float* __restrict__ mu,
    const float* __restrict__ lv, const float* __restrict__ eps,
    float* __restrict__ enc, float* __restrict__ kld)
{
  const int idx = blockIdx.x * 256 + threadIdx.x;
  const float m = mu[idx], l = lv[idx];
  enc[idx] = eps[idx] * expf(0.5f * l) + m;
  float term = 1.0f + l - m * m - expf(l);
  __shared__ float red[256];
  red[threadIdx.x] = term;
  __syncthreads();
  for (int s = 128; s > 0; s >>= 1) {
    if (threadIdx.x < s) red[threadIdx.x] += red[threadIdx.x + s];
    __syncthreads();
  }
  if (threadIdx.x == 0) atomicAdd(kld, -0.5f * red[0] / (float)kB);
}

// ---------------- W_comb = w_ih0 @ d_fc2w; b_comb; gvec0 --------------------
__global__ __launch_bounds__(256) void prep_comb(const float* __restrict__ wih0,
    const float* __restrict__ bih0, const float* __restrict__ fc2w,
    const float* __restrict__ fc2b, float* __restrict__ Wc,
    float* __restrict__ bc, float* __restrict__ g0)
{
  const int idx = blockIdx.x * 256 + threadIdx.x;   // < 1536*512
  const int n = idx >> 9, j = idx & 511;
  float s = 0.f;
#pragma unroll
  for (int v = 0; v < kV; ++v) s = fmaf(wih0[n * kV + v], fc2w[v * kH + j], s);
  Wc[idx] = s;
  if (j == 0) {
    float sb = 0.f;
    for (int v = 0; v < kV; ++v) sb = fmaf(wih0[n * kV + v], fc2b[v], sb);
    bc[n] = bih0[n] + sb;
  }
  if (j == 1) g0[n] = wih0[n * kV + 41] + bih0[n];
}

__global__ __launch_bounds__(256) void transp_fc2w(const float* __restrict__ fc2w,
                                                   float* __restrict__ fc2wT)
{
  const int idx = blockIdx.x * 256 + threadIdx.x;
  if (idx < kH * kV) {
    const int j = idx / kV, v = idx - j * kV;
    fc2wT[idx] = fc2w[v * kH + j];
  }
}

// ---------------- persistent GRU decoder ------------------------------------
__device__ __forceinline__ float sigm(float x) { return 1.f / (1.f + expf(-x)); }

__device__ __forceinline__ void project_out(const float* __restrict__ h1T,
    const float* __restrict__ fc2wT, const float* __restrict__ fc2b,
    float* __restrict__ out, float* proj, int j0, int tid, int tt)
{
  if (tid < 168) {
    const int bb = tid / 84, rem = tid % 84, jh = rem / 42, v = rem % 42;
    const int b = j0 + bb;
    const int jbase = jh * 256;
    float s = 0.f;
#pragma unroll 4
    for (int jj = 0; jj < 256; ++jj)
      s = fmaf(h1T[(size_t)(jbase + jj) * kB + b], fc2wT[(jbase + jj) * kV + v], s);
    proj[tid] = s;
  }
  __syncthreads();
  if (tid < 168 && (tid % 84) < 42) {
    const int bb = tid / 84, v = tid % 84;
    out[(size_t)(j0 + bb) * (kSEQ * kV) + (size_t)tt * kV + v] =
        proj[tid] + proj[tid + 42] + fc2b[v];
  }
  __syncthreads();
}

__global__ __launch_bounds__(256, 1) void gru_persist(
    const float* __restrict__ Wc, const float* __restrict__ whh0,
    const float* __restrict__ wih1, const float* __restrict__ whh1,
    const float* __restrict__ bc, const float* __restrict__ g0,
    const float* __restrict__ bhh0, const float* __restrict__ bih1,
    const float* __restrict__ bhh1, const float* __restrict__ fc2wT,
    const float* __restrict__ fc2b,
    float* h0a, float* h0b, float* h1a, float* h1b,
    float* __restrict__ out)
{
  __shared__ float wlds[24][512];   // 48 KB: block's 24 persistent weight rows
  __shared__ float proj[256];
  const int tid = threadIdx.x;
  const int bid = blockIdx.x;
  const int j0 = bid * 2;
  const int rg = tid & 1;          // which of the block's 2 j-columns
  const int b4 = (tid >> 1) * 4;   // 4-batch slice
  const int j = j0 + rg;

  // ---- one-time: load 24 weight rows (per j: gi0 r,z,n | gh0 r,z,n | gh1 r,z,n ; gi1 r,z,n)
  for (int i = tid; i < 24 * 128; i += 256) {
    const int rr = i >> 7;
    const int c = (i & 127) << 2;
    const float* src;
    if (rr < 18) {
      const int rgr = rr / 9, q = rr % 9;
      const int row = (q % 3) * kH + j0 + rgr;
      src = (q < 3) ? (Wc + (size_t)row * kH)
          : (q < 6) ? (whh0 + (size_t)row * kH)
                    : (whh1 + (size_t)row * kH);
    } else {
      const int rgr = (rr - 18) / 3, g = (rr - 18) % 3;
      src = wih1 + (size_t)(g * kH + j0 + rgr) * kH;
    }
    *(float4*)&wlds[rr][c] = *(const float4*)(src + c);
  }
  __syncthreads();

  cg::grid_group grid = cg::this_grid();

  float* h0cur = h0a; float* h0nxt = h0b;
  float* h1cur = h1a; float* h1nxt = h1b;

  for (int t = 0; t < kSEQ; ++t) {
    if (t > 0) project_out(h1cur, fc2wT, fc2b, out, proj, j0, tid, t - 1);

    // ---- phase A: gi0 (A=h1cur), gh0 (A=h0cur), gh1 (A=h1cur); 9 rows x 4 b
    const float* gib = (t == 0) ? g0 : bc;   // h1cur==0 at t=0, so GEMM adds 0
    float4 acc[9];
#pragma unroll
    for (int q = 0; q < 9; ++q) {
      const float bv = (q < 3) ? gib[q * kH + j]
                     : (q < 6) ? bhh0[(q - 3) * kH + j]
                               : bhh1[(q - 6) * kH + j];
      acc[q] = make_float4(bv, bv, bv, bv);
    }
#pragma unroll 2
    for (int kk = 0; kk < kH; kk += 4) {
      float4 a1[4], a0[4];
#pragma unroll
      for (int u = 0; u < 4; ++u) {
        a1[u] = *(const float4*)(h1cur + (size_t)(kk + u) * kB + b4);
        a0[u] = *(const float4*)(h0cur + (size_t)(kk + u) * kB + b4);
      }
#pragma unroll
      for (int q = 0; q < 9; ++q) {
        const float4 w = *(const float4*)&wlds[rg * 9 + q][kk];
        const float4* Ap = (q >= 3 && q < 6) ? a0 : a1;
#pragma unroll
        for (int u = 0; u < 4; ++u) {
          const float wu = (u == 0) ? w.x : (u == 1) ? w.y : (u == 2) ? w.z : w.w;
          acc[q].x = fmaf(wu, Ap[u].x, acc[q].x);
          acc[q].y = fmaf(wu, Ap[u].y, acc[q].y);
          acc[q].z = fmaf(wu, Ap[u].z, acc[q].z);
          acc[q].w = fmaf(wu, Ap[u].w, acc[q].w);
        }
      }
    }
    // gate math layer 0
    const float4 hp0 = *(const float4*)(h0cur + (size_t)j * kB + b4);
    float4 h0n;
#define GATE0(C) { \
    const float r_ = sigm(acc[0].C + acc[3].C); \
    const float z_ = sigm(acc[1].C + acc[4].C); \
    const float n_ = tanhf(acc[2].C + r_ * acc[5].C); \
    h0n.C = (1.f - z_) * n_ + z_ * hp0.C; }
    GATE0(x) GATE0(y) GATE0(z) GATE0(w)
#undef GATE0
    *(float4*)(h0nxt + (size_t)j * kB + b4) = h0n;

    grid.sync();

    // ---- phase B: gi1 (A=h0nxt); gh1 carried in acc[6..8]
    float4 c3[3];
#pragma unroll
    for (int g = 0; g < 3; ++g) {
      const float bv = bih1[g * kH + j];
      c3[g] = make_float4(bv, bv, bv, bv);
    }
#pragma unroll 2
    for (int kk = 0; kk < kH; kk += 4) {
      float4 a[4];
#pragma unroll
      for (int u = 0; u < 4; ++u)
        a[u] = *(const float4*)(h0nxt + (size_t)(kk + u) * kB + b4);
#pragma unroll
      for (int g = 0; g < 3; ++g) {
        const float4 w = *(const float4*)&wlds[18 + rg * 3 + g][kk];
#pragma unroll
        for (int u = 0; u < 4; ++u) {
          const float wu = (u == 0) ? w.x : (u == 1) ? w.y : (u == 2) ? w.z : w.w;
          c3[g].x = fmaf(wu, a[u].x, c3[g].x);
          c3[g].y = fmaf(wu, a[u].y, c3[g].y);
          c3[g].z = fmaf(wu, a[u].z, c3[g].z);
          c3[g].w = fmaf(wu, a[u].w, c3[g].w);
        }
      }
    }
    const float4 hp1 = *(const float4*)(h1cur + (size_t)j * kB + b4);
    float4 h1n;
#define GATE1(C) { \
    const float r_ = sigm(c3[0].C + acc[6].C); \
    const float z_ = sigm(c3[1].C + acc[7].C); \
    const float n_ = tanhf(c3[2].C + r_ * acc[8].C); \
    h1n.C = (1.f - z_) * n_ + z_ * hp1.C; }
    GATE1(x) GATE1(y) GATE1(z) GATE1(w)
#undef GATE1
    *(float4*)(h1nxt + (size_t)j * kB + b4) = h1n;

    grid.sync();
    float* tmp;
    tmp = h0cur; h0cur = h0nxt; h0nxt = tmp;
    tmp = h1cur; h1cur = h1nxt; h1nxt = tmp;
  }
  project_out(h1cur, fc2wT, fc2b, out, proj, j0, tid, kSEQ - 1);
}

extern "C" void kernel_launch(void* const* d_in, const int* in_sizes, int n_in,
                              void* d_out, int out_size, void* d_ws, size_t ws_size,
                              hipStream_t stream) {
  const float* X    = (const float*)d_in[0];
  const float* eps  = (const float*)d_in[2];
  const float* e1w  = (const float*)d_in[3];  const float* e1b  = (const float*)d_in[4];
  const float* e2w  = (const float*)d_in[5];  const float* e2b  = (const float*)d_in[6];
  const float* e3w  = (const float*)d_in[7];  const float* e3b  = (const float*)d_in[8];
  const float* e41w = (const float*)d_in[9];  const float* e41b = (const float*)d_in[10];
  const float* e42w = (const float*)d_in[11]; const float* e42b = (const float*)d_in[12];
  const float* fc1w = (const float*)d_in[13]; const float* fc1b = (const float*)d_in[14];
  const float* fc2w = (const float*)d_in[15]; const float* fc2b = (const float*)d_in[16];
  const float* wih0 = (const float*)d_in[17]; const float* bih0 = (const float*)d_in[18];
  const float* whh0 = (const float*)d_in[19]; const float* bhh0 = (const float*)d_in[20];
  const float* wih1 = (const float*)d_in[21]; const float* bih1 = (const float*)d_in[22];
  const float* whh1 = (const float*)d_in[23]; const float* bhh1 = (const float*)d_in[24];
  float* out = (float*)d_out;

  float* ws = (float*)d_ws;
  // Region plan (float offsets); aliases are safe by stream ordering:
  //   [0, 1048576)        eh1  -> later Wc/bc/g0/fc2wT (eh1 dead after gemm2)
  //   [1048576, 1572864)  eh2  -> later h0a/h0b        (eh2 dead after gemm3)
  //   [1572864, 1835008)  eh3  -> later h1a            (eh3 dead after gemm5)
  //   [1835008, 2097152)  h1b
  //   [2097152, ...)      mu, lv, enc
  float* eh1   = ws;
  float* Wc    = ws;
  float* bc    = ws + 786432;
  float* g0    = ws + 787968;
  float* fc2wT = ws + 789504;
  float* eh2   = ws + 1048576;
  float* h0a   = ws + 1048576;
  float* h0b   = ws + 1310720;
  float* eh3   = ws + 1572864;
  float* h1a   = ws + 1572864;
  float* h1b   = ws + 1835008;
  float* mu    = ws + 2097152;
  float* lv    = ws + 2129920;
  float* enc   = ws + 2162688;

  const size_t dec_elems = (size_t)kB * kSEQ * kV;

  // ---- encoder ----
  gemm_bias<true , false><<<dim3(32, 8), 256, 0, stream>>>(X,   e1w, e1b, eh1, kB, 2048, 4096);
  gemm_bias<true , false><<<dim3(16, 8), 256, 0, stream>>>(eh1, e2w, e2b, eh2, kB, 1024, 2048);
  gemm_bias<true , false><<<dim3( 8, 8), 256, 0, stream>>>(eh2, e3w, e3b, eh3, kB,  512, 1024);
  gemm_bias<false, false><<<dim3( 1, 8), 256, 0, stream>>>(eh3, e41w, e41b, mu, kB,   64,  512);
  gemm_bias<false, false><<<dim3( 1, 8), 256, 0, stream>>>(eh3, e42w, e42b, lv, kB,   64,  512);
  hipMemsetAsync(out + dec_elems, 0, sizeof(float), stream);
  enc_kld<<<128, 256, 0, stream>>>(mu, lv, eps, enc, out + dec_elems);
  // lat, written transposed into h0a (h0T layout [j][b]); h0a aliases eh2 (dead)
  gemm_bias<false, true ><<<dim3(8, 8), 256, 0, stream>>>(enc, fc1w, fc1b, h0a, kB, kH, kENC);
  // prep: Wc/bc/g0 alias eh1 (dead after gemm2); fc2wT transpose
  prep_comb<<<3072, 256, 0, stream>>>(wih0, bih0, fc2w, fc2b, Wc, bc, g0);
  transp_fc2w<<<(kH * kV + 255) / 256, 256, 0, stream>>>(fc2w, fc2wT);
  hipMemsetAsync(h1a, 0, (size_t)kB * kH * sizeof(float), stream);  // h_l1(-1)=0; aliases eh3 (dead)

  // ---- persistent GRU decoder: 128 steps, 2 grid syncs/step ----
  void* args[] = { (void*)&Wc, (void*)&whh0, (void*)&wih1, (void*)&whh1,
                   (void*)&bc, (void*)&g0, (void*)&bhh0, (void*)&bih1,
                   (void*)&bhh1, (void*)&fc2wT, (void*)&fc2b,
                   (void*)&h0a, (void*)&h0b, (void*)&h1a, (void*)&h1b,
                   (void*)&out };
  hipLaunchCooperativeKernel((void*)gru_persist, dim3(256), dim3(256), args, 0, stream);
}

// Round 3
// 17011.269 us; speedup vs baseline: 1.4455x; 1.4272x over previous
//
#include <hip/hip_runtime.h>
#include <hip/hip_cooperative_groups.h>
#include <math.h>

namespace cg = cooperative_groups;

constexpr int kB = 512, kENC = 64, kH = 512, kV = 42, kSEQ = 128;

typedef __attribute__((ext_vector_type(8))) short bf16x8;
typedef __attribute__((ext_vector_type(4))) float f32x4;

__device__ __forceinline__ unsigned short f2bf(float x) {
  union { float f; unsigned u; } c; c.f = x;
  unsigned r = c.u + 0x7FFFu + ((c.u >> 16) & 1u);
  return (unsigned short)(r >> 16);
}
__device__ __forceinline__ float sigm(float x) { return 1.f / (1.f + expf(-x)); }

// ---------------- generic SGEMM: C[M,N] = act(A[M,K] @ W[N,K]^T + bias[N]) ----
template<bool RELU>
__global__ __launch_bounds__(256) void gemm_bias(const float* __restrict__ A,
    const float* __restrict__ W, const float* __restrict__ bias,
    float* __restrict__ C, int M, int N, int K)
{
  __shared__ float As[16][68];
  __shared__ float Bs[16][68];
  const int tid = threadIdx.x;
  const int n0 = blockIdx.x * 64;
  const int m0 = blockIdx.y * 64;
  const int tx = tid & 15;
  const int ty = tid >> 4;
  const int lr = tid >> 2;
  const int lk = (tid & 3) << 2;
  float acc[4][4] = {};
  for (int kc = 0; kc < K; kc += 16) {
    const float4 va = *(const float4*)(A + (size_t)(m0 + lr) * K + kc + lk);
    const float4 vb = *(const float4*)(W + (size_t)(n0 + lr) * K + kc + lk);
    __syncthreads();
    As[lk+0][lr] = va.x; As[lk+1][lr] = va.y; As[lk+2][lr] = va.z; As[lk+3][lr] = va.w;
    Bs[lk+0][lr] = vb.x; Bs[lk+1][lr] = vb.y; Bs[lk+2][lr] = vb.z; Bs[lk+3][lr] = vb.w;
    __syncthreads();
#pragma unroll
    for (int k = 0; k < 16; ++k) {
      const float4 a = *(const float4*)&As[k][ty << 2];
      const float4 b = *(const float4*)&Bs[k][tx << 2];
      const float av[4] = {a.x, a.y, a.z, a.w};
      const float bv[4] = {b.x, b.y, b.z, b.w};
#pragma unroll
      for (int i = 0; i < 4; ++i)
#pragma unroll
        for (int j = 0; j < 4; ++j) acc[i][j] = fmaf(av[i], bv[j], acc[i][j]);
    }
  }
  const int cn = n0 + (tx << 2);
  const float4 b4 = *(const float4*)&bias[cn];
  const float bvv[4] = {b4.x, b4.y, b4.z, b4.w};
#pragma unroll
  for (int i = 0; i < 4; ++i) {
    float4 o;
    float* op = &o.x;
#pragma unroll
    for (int j = 0; j < 4; ++j) {
      float v = acc[i][j] + bvv[j];
      if (RELU) v = fmaxf(v, 0.f);
      op[j] = v;
    }
    *(float4*)(C + (size_t)(m0 + (ty << 2) + i) * N + cn) = o;
  }
}

// ---------------- encoded = eps*exp(0.5*logvar)+mu; kld reduce ---------------
__global__ __launch_bounds__(256) void enc_kld(const float* __restrict__ mu,
    const float* __restrict__ lv, const float* __restrict__ eps,
    float* __restrict__ enc, float* __restrict__ kld)
{
  const int idx = blockIdx.x * 256 + threadIdx.x;
  const float m = mu[idx], l = lv[idx];
  enc[idx] = eps[idx] * expf(0.5f * l) + m;
  float term = 1.0f + l - m * m - expf(l);
  __shared__ float red[256];
  red[threadIdx.x] = term;
  __syncthreads();
  for (int s = 128; s > 0; s >>= 1) {
    if (threadIdx.x < s) red[threadIdx.x] += red[threadIdx.x + s];
    __syncthreads();
  }
  if (threadIdx.x == 0) atomicAdd(kld, -0.5f * red[0] / (float)kB);
}

// ---------------- W_comb = w_ih0 @ d_fc2w (bf16 out); b_comb; gvec0 ----------
__global__ __launch_bounds__(256) void prep_comb(const float* __restrict__ wih0,
    const float* __restrict__ bih0, const float* __restrict__ fc2w,
    const float* __restrict__ fc2b, unsigned short* __restrict__ Wcb,
    float* __restrict__ bc, float* __restrict__ g0)
{
  const int idx = blockIdx.x * 256 + threadIdx.x;   // < 1536*512
  const int n = idx >> 9, j = idx & 511;
  float s = 0.f;
#pragma unroll
  for (int v = 0; v < kV; ++v) s = fmaf(wih0[n * kV + v], fc2w[v * kH + j], s);
  Wcb[idx] = f2bf(s);
  if (j == 0) {
    float sb = 0.f;
    for (int v = 0; v < kV; ++v) sb = fmaf(wih0[n * kV + v], fc2b[v], sb);
    bc[n] = bih0[n] + sb;
  }
  if (j == 1) g0[n] = wih0[n * kV + 41] + bih0[n];
}

__global__ __launch_bounds__(256) void conv_bf16(const float* __restrict__ s,
                                                 unsigned short* __restrict__ d, int n)
{
  const int i = blockIdx.x * 256 + threadIdx.x;
  if (i < n) d[i] = f2bf(s[i]);
}

__global__ __launch_bounds__(256) void conv_fc2w_pad(const float* __restrict__ fc2w,
                                                     unsigned short* __restrict__ d)
{
  const int i = blockIdx.x * 256 + threadIdx.x;   // < 48*512
  if (i < 48 * kH) {
    const int r = i >> 9, k = i & 511;
    d[i] = (r < kV) ? f2bf(fc2w[r * kH + k]) : 0;
  }
}

// ---------------- persistent MFMA GRU decoder --------------------------------
// grid = 256: jg = bid>>3 (16 js), mg = bid&7 (64 batches)
// per step: phase A (gi0|gh0|gh1 per-wave + fused out-proj) -> LDS C combine ->
// gate L0 -> grid.sync -> phase B (gi1) -> gate L1 -> grid.sync
__global__ __launch_bounds__(256, 1) void gru_mfma(
    const unsigned short* __restrict__ Wcb, const unsigned short* __restrict__ whh0b,
    const unsigned short* __restrict__ wih1b, const unsigned short* __restrict__ whh1b,
    const unsigned short* __restrict__ fc2wb,
    const float* __restrict__ bc, const float* __restrict__ g0,
    const float* __restrict__ bhh0, const float* __restrict__ bih1,
    const float* __restrict__ bhh1, const float* __restrict__ fc2b,
    const float* __restrict__ latg,
    unsigned short* h0A, unsigned short* h0B,
    unsigned short* h1A, unsigned short* h1B,
    float* __restrict__ out)
{
  __shared__ float Cs[12][16][65];   // [tile][j-local][m-local + pad]
  const int tid = threadIdx.x;
  const int wave = tid >> 6;
  const int lane = tid & 63;
  const int quad = lane >> 4;
  const int flr = lane & 15;
  const int flk = quad * 8;
  const int bid = blockIdx.x;
  const int jg = bid >> 3, mg = bid & 7;
  const int m0 = mg * 64;
  const int jbase = jg * 16;
  const bool projw = (jg == 0) && (wave >= 2);
  const int mtb = (wave == 3) ? 2 : 0;   // proj m-tile base

  // gate-math item mapping: thread -> (m = tid>>2, 4 consecutive local js)
  const int gmm = tid >> 2;
  const int gmb = m0 + gmm;
  const int jl0 = (tid & 3) << 2;
  const int gj = jbase + jl0;

  float hp0[4], hp1[4];
  {
    const float4 l4 = *(const float4*)(latg + (size_t)gmb * kH + gj);
    hp0[0] = l4.x; hp0[1] = l4.y; hp0[2] = l4.z; hp0[3] = l4.w;
    hp1[0] = hp1[1] = hp1[2] = hp1[3] = 0.f;
  }

  // wave roles in phase A (waves 2&3 both compute full gh1 -> benign dup writes)
  const int csb = (wave == 0) ? 0 : (wave == 1) ? 3 : 6;
  const unsigned short* BwA = (wave == 0) ? Wcb : (wave == 1) ? whh0b : whh1b;

  float fb[3];
#pragma unroll
  for (int nt = 0; nt < 3; ++nt) {
    const int v = nt * 16 + flr;
    fb[nt] = (v < kV) ? fc2b[v] : 0.f;
  }

  cg::grid_group grid = cg::this_grid();

  const unsigned short* h0c = h0A; unsigned short* h0n = h0B;
  const unsigned short* h1c = h1A; unsigned short* h1n = h1B;
  const f32x4 zf = {0.f, 0.f, 0.f, 0.f};

  for (int t = 0; t < kSEQ; ++t) {
    // ---------- phase A ----------
    {
      const unsigned short* Ac = (wave == 1) ? h0c : h1c;
      const unsigned short* Ap = Ac + (size_t)(m0 + flr) * kH + flk;
      const unsigned short* Bp = BwA + (size_t)(jbase + flr) * kH + flk;
      const unsigned short* Pp = fc2wb + (size_t)flr * kH + flk;
      f32x4 acc[3][4];
      f32x4 pacc[3][2];
#pragma unroll
      for (int g = 0; g < 3; ++g) {
#pragma unroll
        for (int mt = 0; mt < 4; ++mt) acc[g][mt] = zf;
        pacc[g][0] = zf; pacc[g][1] = zf;
      }
      const bool dop = projw && (t > 0);
#pragma unroll 2
      for (int kf = 0; kf < 16; ++kf) {
        const int ko = kf * 32;
        bf16x8 a[4], b[3];
#pragma unroll
        for (int mt = 0; mt < 4; ++mt)
          a[mt] = *(const bf16x8*)(Ap + (size_t)mt * (16 * kH) + ko);
#pragma unroll
        for (int g = 0; g < 3; ++g)
          b[g] = *(const bf16x8*)(Bp + (size_t)g * (kH * kH) + ko);
#pragma unroll
        for (int g = 0; g < 3; ++g)
#pragma unroll
          for (int mt = 0; mt < 4; ++mt)
            acc[g][mt] = __builtin_amdgcn_mfma_f32_16x16x32_bf16(a[mt], b[g], acc[g][mt], 0, 0, 0);
        if (dop) {
#pragma unroll
          for (int nt = 0; nt < 3; ++nt) {
            const bf16x8 pb = *(const bf16x8*)(Pp + (size_t)nt * (16 * kH) + ko);
#pragma unroll
            for (int mt = 0; mt < 2; ++mt)
              pacc[nt][mt] = __builtin_amdgcn_mfma_f32_16x16x32_bf16(a[mtb + mt], pb, pacc[nt][mt], 0, 0, 0);
          }
        }
      }
#pragma unroll
      for (int g = 0; g < 3; ++g)
#pragma unroll
        for (int mt = 0; mt < 4; ++mt)
#pragma unroll
          for (int r = 0; r < 4; ++r)
            Cs[csb + g][flr][mt * 16 + quad * 4 + r] = acc[g][mt][r];
      if (dop) {
#pragma unroll
        for (int nt = 0; nt < 3; ++nt) {
          const int v = nt * 16 + flr;
          if (v < kV) {
#pragma unroll
            for (int mt = 0; mt < 2; ++mt)
#pragma unroll
              for (int r = 0; r < 4; ++r)
                out[(size_t)(m0 + (mtb + mt) * 16 + quad * 4 + r) * (kSEQ * kV)
                    + (size_t)(t - 1) * kV + v] = pacc[nt][mt][r] + fb[nt];
          }
        }
      }
    }
    __syncthreads();
    // ---------- gate math layer 0 ----------
    {
      const float* bi = (t == 0) ? g0 : bc;
      float bir[4], biz[4], bin[4], bhr[4], bhz[4], bhn[4];
      *(float4*)bir = *(const float4*)(bi + gj);
      *(float4*)biz = *(const float4*)(bi + kH + gj);
      *(float4*)bin = *(const float4*)(bi + 2 * kH + gj);
      *(float4*)bhr = *(const float4*)(bhh0 + gj);
      *(float4*)bhz = *(const float4*)(bhh0 + kH + gj);
      *(float4*)bhn = *(const float4*)(bhh0 + 2 * kH + gj);
      ushort4 pk;
      unsigned short* pkp = (unsigned short*)&pk;
#pragma unroll
      for (int i = 0; i < 4; ++i) {
        const float gir = Cs[0][jl0 + i][gmm] + bir[i];
        const float giz = Cs[1][jl0 + i][gmm] + biz[i];
        const float gin = Cs[2][jl0 + i][gmm] + bin[i];
        const float ghr = Cs[3][jl0 + i][gmm] + bhr[i];
        const float ghz = Cs[4][jl0 + i][gmm] + bhz[i];
        const float ghn = Cs[5][jl0 + i][gmm] + bhn[i];
        const float r = sigm(gir + ghr);
        const float z = sigm(giz + ghz);
        const float n = tanhf(gin + r * ghn);
        const float h = (1.f - z) * n + z * hp0[i];
        hp0[i] = h;
        pkp[i] = f2bf(h);
      }
      *(ushort4*)(h0n + (size_t)gmb * kH + gj) = pk;
    }
    grid.sync();
    // ---------- phase B: gi1 = h0n @ wih1^T (m-split waves) ----------
    {
      const unsigned short* Ap = h0n + (size_t)(m0 + wave * 16 + flr) * kH + flk;
      const unsigned short* Bp = wih1b + (size_t)(jbase + flr) * kH + flk;
      f32x4 c2[3] = {zf, zf, zf};
#pragma unroll 2
      for (int kf = 0; kf < 16; ++kf) {
        const int ko = kf * 32;
        const bf16x8 a = *(const bf16x8*)(Ap + ko);
        bf16x8 b[3];
#pragma unroll
        for (int g = 0; g < 3; ++g)
          b[g] = *(const bf16x8*)(Bp + (size_t)g * (kH * kH) + ko);
#pragma unroll
        for (int g = 0; g < 3; ++g)
          c2[g] = __builtin_amdgcn_mfma_f32_16x16x32_bf16(a, b[g], c2[g], 0, 0, 0);
      }
#pragma unroll
      for (int g = 0; g < 3; ++g)
#pragma unroll
        for (int r = 0; r < 4; ++r)
          Cs[9 + g][flr][wave * 16 + quad * 4 + r] = c2[g][r];
    }
    __syncthreads();
    // ---------- gate math layer 1 ----------
    {
      float bir[4], biz[4], bin[4], bhr[4], bhz[4], bhn[4];
      *(float4*)bir = *(const float4*)(bih1 + gj);
      *(float4*)biz = *(const float4*)(bih1 + kH + gj);
      *(float4*)bin = *(const float4*)(bih1 + 2 * kH + gj);
      *(float4*)bhr = *(const float4*)(bhh1 + gj);
      *(float4*)bhz = *(const float4*)(bhh1 + kH + gj);
      *(float4*)bhn = *(const float4*)(bhh1 + 2 * kH + gj);
      ushort4 pk;
      unsigned short* pkp = (unsigned short*)&pk;
#pragma unroll
      for (int i = 0; i < 4; ++i) {
        const float gir = Cs[9][jl0 + i][gmm] + bir[i];
        const float giz = Cs[10][jl0 + i][gmm] + biz[i];
        const float gin = Cs[11][jl0 + i][gmm] + bin[i];
        const float ghr = Cs[6][jl0 + i][gmm] + bhr[i];
        const float ghz = Cs[7][jl0 + i][gmm] + bhz[i];
        const float ghn = Cs[8][jl0 + i][gmm] + bhn[i];
        const float r = sigm(gir + ghr);
        const float z = sigm(giz + ghz);
        const float n = tanhf(gin + r * ghn);
        const float h = (1.f - z) * n + z * hp1[i];
        hp1[i] = h;
        pkp[i] = f2bf(h);
      }
      *(ushort4*)(h1n + (size_t)gmb * kH + gj) = pk;
    }
    grid.sync();
    {
      const unsigned short* tc;
      tc = h0c; h0c = h0n; h0n = (unsigned short*)tc;
      tc = h1c; h1c = h1n; h1n = (unsigned short*)tc;
    }
  }
  // ---------- tail projection: out[127] from final h1 ----------
  if (projw) {
    const unsigned short* Ap = h1c + (size_t)(m0 + mtb * 16 + flr) * kH + flk;
    const unsigned short* Pp = fc2wb + (size_t)flr * kH + flk;
    f32x4 pacc[3][2];
#pragma unroll
    for (int g = 0; g < 3; ++g) { pacc[g][0] = zf; pacc[g][1] = zf; }
#pragma unroll 2
    for (int kf = 0; kf < 16; ++kf) {
      const int ko = kf * 32;
      bf16x8 a[2];
      a[0] = *(const bf16x8*)(Ap + ko);
      a[1] = *(const bf16x8*)(Ap + (size_t)16 * kH + ko);
#pragma unroll
      for (int nt = 0; nt < 3; ++nt) {
        const bf16x8 pb = *(const bf16x8*)(Pp + (size_t)nt * (16 * kH) + ko);
#pragma unroll
        for (int mt = 0; mt < 2; ++mt)
          pacc[nt][mt] = __builtin_amdgcn_mfma_f32_16x16x32_bf16(a[mt], pb, pacc[nt][mt], 0, 0, 0);
      }
    }
#pragma unroll
    for (int nt = 0; nt < 3; ++nt) {
      const int v = nt * 16 + flr;
      if (v < kV) {
#pragma unroll
        for (int mt = 0; mt < 2; ++mt)
#pragma unroll
          for (int r = 0; r < 4; ++r)
            out[(size_t)(m0 + (mtb + mt) * 16 + quad * 4 + r) * (kSEQ * kV)
                + (size_t)(kSEQ - 1) * kV + v] = pacc[nt][mt][r] + fb[nt];
      }
    }
  }
}

extern "C" void kernel_launch(void* const* d_in, const int* in_sizes, int n_in,
                              void* d_out, int out_size, void* d_ws, size_t ws_size,
                              hipStream_t stream) {
  const float* X    = (const float*)d_in[0];
  const float* eps  = (const float*)d_in[2];
  const float* e1w  = (const float*)d_in[3];  const float* e1b  = (const float*)d_in[4];
  const float* e2w  = (const float*)d_in[5];  const float* e2b  = (const float*)d_in[6];
  const float* e3w  = (const float*)d_in[7];  const float* e3b  = (const float*)d_in[8];
  const float* e41w = (const float*)d_in[9];  const float* e41b = (const float*)d_in[10];
  const float* e42w = (const float*)d_in[11]; const float* e42b = (const float*)d_in[12];
  const float* fc1w = (const float*)d_in[13]; const float* fc1b = (const float*)d_in[14];
  const float* fc2w = (const float*)d_in[15]; const float* fc2b = (const float*)d_in[16];
  const float* wih0 = (const float*)d_in[17]; const float* bih0 = (const float*)d_in[18];
  const float* whh0 = (const float*)d_in[19]; const float* bhh0 = (const float*)d_in[20];
  const float* wih1 = (const float*)d_in[21]; const float* bih1 = (const float*)d_in[22];
  const float* whh1 = (const float*)d_in[23]; const float* bhh1 = (const float*)d_in[24];
  float* out = (float*)d_out;

  float* ws = (float*)d_ws;
  // float-offset workspace plan (aliases safe by stream order):
  //   region A [0,1048576) = eh1; reused after gemm2 by Wcb/whh0b/fc2wb
  //   region B [1048576,1572864) = eh2; reused after gemm3 by wih1b
  //   region C [1572864,1835008) = eh3; overlapped by whh1b tail (after gemm4/5)
  float* eh1 = ws;
  unsigned short* Wcb   = (unsigned short*)(ws + 0);        // 786432 us
  unsigned short* whh0b = (unsigned short*)(ws + 393216);   // 786432 us
  unsigned short* fc2wb = (unsigned short*)(ws + 786432);   // 24576 us
  float* eh2 = ws + 1048576;
  unsigned short* wih1b = (unsigned short*)(ws + 1048576);  // 786432 us
  unsigned short* whh1b = (unsigned short*)(ws + 1441792);  // 786432 us (tail overlaps eh3)
  float* eh3 = ws + 1572864;
  float* latg = ws + 1835008;                               // 262144 f
  unsigned short* h0a = (unsigned short*)(ws + 2097152);    // 262144 us each
  unsigned short* h0b = (unsigned short*)(ws + 2228224);
  unsigned short* h1a = (unsigned short*)(ws + 2359296);
  unsigned short* h1b = (unsigned short*)(ws + 2490368);
  float* mu  = ws + 2621440;
  float* lv  = ws + 2654208;
  float* enc = ws + 2686976;
  float* bc  = ws + 2719744;
  float* g0  = ws + 2721280;

  const size_t dec_elems = (size_t)kB * kSEQ * kV;

  // ---- encoder ----
  gemm_bias<true ><<<dim3(32, 8), 256, 0, stream>>>(X,   e1w, e1b, eh1, kB, 2048, 4096);
  gemm_bias<true ><<<dim3(16, 8), 256, 0, stream>>>(eh1, e2w, e2b, eh2, kB, 1024, 2048);
  gemm_bias<true ><<<dim3( 8, 8), 256, 0, stream>>>(eh2, e3w, e3b, eh3, kB,  512, 1024);
  gemm_bias<false><<<dim3( 1, 8), 256, 0, stream>>>(eh3, e41w, e41b, mu, kB,   64,  512);
  gemm_bias<false><<<dim3( 1, 8), 256, 0, stream>>>(eh3, e42w, e42b, lv, kB,   64,  512);
  hipMemsetAsync(out + dec_elems, 0, sizeof(float), stream);
  enc_kld<<<128, 256, 0, stream>>>(mu, lv, eps, enc, out + dec_elems);
  gemm_bias<false><<<dim3(8, 8), 256, 0, stream>>>(enc, fc1w, fc1b, latg, kB, kH, kENC);

  // ---- weight prep (bf16) ----
  prep_comb<<<3072, 256, 0, stream>>>(wih0, bih0, fc2w, fc2b, Wcb, bc, g0);
  conv_bf16<<<3072, 256, 0, stream>>>(whh0, whh0b, 1536 * kH);
  conv_bf16<<<3072, 256, 0, stream>>>(wih1, wih1b, 1536 * kH);
  conv_bf16<<<3072, 256, 0, stream>>>(whh1, whh1b, 1536 * kH);
  conv_fc2w_pad<<<96, 256, 0, stream>>>(fc2w, fc2wb);
  conv_bf16<<<1024, 256, 0, stream>>>(latg, h0a, kB * kH);
  hipMemsetAsync(h1a, 0, (size_t)kB * kH * sizeof(unsigned short), stream);

  // ---- persistent MFMA GRU decoder ----
  void* args[] = { (void*)&Wcb, (void*)&whh0b, (void*)&wih1b, (void*)&whh1b,
                   (void*)&fc2wb, (void*)&bc, (void*)&g0, (void*)&bhh0,
                   (void*)&bih1, (void*)&bhh1, (void*)&fc2b, (void*)&latg,
                   (void*)&h0a, (void*)&h0b, (void*)&h1a, (void*)&h1b,
                   (void*)&out };
  hipLaunchCooperativeKernel((void*)gru_mfma, dim3(256), dim3(256), args, 0, stream);
}

// Round 4
// 10781.014 us; speedup vs baseline: 2.2808x; 1.5779x over previous
//
#include <hip/hip_runtime.h>
#include <hip/hip_cooperative_groups.h>
#include <math.h>

namespace cg = cooperative_groups;

constexpr int kB = 512, kENC = 64, kH = 512, kV = 42, kSEQ = 128;
constexpr int kWPitch = 520;                    // bf16 LDS row pitch (bank-skewed)
constexpr int kWRows  = 96;                     // 48 T0 (Wc|whh1) + 24 whh0 + 24 wih1
constexpr int kZPad   = kWRows * kWPitch;       // 49920: 32 bf16 zeros
constexpr int kCsAByte = (kZPad + 32) * 2;      // 99904
constexpr int kLdsBytes = kCsAByte + 30720 + 15360;  // 145984

typedef __attribute__((ext_vector_type(8))) short bf16x8;
typedef __attribute__((ext_vector_type(4))) float f32x4;

__device__ __forceinline__ unsigned short f2bf(float x) {
  union { float f; unsigned u; } c; c.f = x;
  unsigned r = c.u + 0x7FFFu + ((c.u >> 16) & 1u);
  return (unsigned short)(r >> 16);
}
__device__ __forceinline__ float sigm(float x) { return 1.f / (1.f + expf(-x)); }

// ---------------- generic SGEMM: C[M,N] = act(A[M,K] @ W[N,K]^T + bias[N]) ----
template<bool RELU>
__global__ __launch_bounds__(256) void gemm_bias(const float* __restrict__ A,
    const float* __restrict__ W, const float* __restrict__ bias,
    float* __restrict__ C, int M, int N, int K)
{
  __shared__ float As[16][68];
  __shared__ float Bs[16][68];
  const int tid = threadIdx.x;
  const int n0 = blockIdx.x * 64;
  const int m0 = blockIdx.y * 64;
  const int tx = tid & 15;
  const int ty = tid >> 4;
  const int lr = tid >> 2;
  const int lk = (tid & 3) << 2;
  float acc[4][4] = {};
  for (int kc = 0; kc < K; kc += 16) {
    const float4 va = *(const float4*)(A + (size_t)(m0 + lr) * K + kc + lk);
    const float4 vb = *(const float4*)(W + (size_t)(n0 + lr) * K + kc + lk);
    __syncthreads();
    As[lk+0][lr] = va.x; As[lk+1][lr] = va.y; As[lk+2][lr] = va.z; As[lk+3][lr] = va.w;
    Bs[lk+0][lr] = vb.x; Bs[lk+1][lr] = vb.y; Bs[lk+2][lr] = vb.z; Bs[lk+3][lr] = vb.w;
    __syncthreads();
#pragma unroll
    for (int k = 0; k < 16; ++k) {
      const float4 a = *(const float4*)&As[k][ty << 2];
      const float4 b = *(const float4*)&Bs[k][tx << 2];
      const float av[4] = {a.x, a.y, a.z, a.w};
      const float bv[4] = {b.x, b.y, b.z, b.w};
#pragma unroll
      for (int i = 0; i < 4; ++i)
#pragma unroll
        for (int jj = 0; jj < 4; ++jj) acc[i][jj] = fmaf(av[i], bv[jj], acc[i][jj]);
    }
  }
  const int cn = n0 + (tx << 2);
  const float4 b4 = *(const float4*)&bias[cn];
  const float bvv[4] = {b4.x, b4.y, b4.z, b4.w};
#pragma unroll
  for (int i = 0; i < 4; ++i) {
    float4 o;
    float* op = &o.x;
#pragma unroll
    for (int jj = 0; jj < 4; ++jj) {
      float v = acc[i][jj] + bvv[jj];
      if (RELU) v = fmaxf(v, 0.f);
      op[jj] = v;
    }
    *(float4*)(C + (size_t)(m0 + (ty << 2) + i) * N + cn) = o;
  }
}

// ---------------- encoded = eps*exp(0.5*logvar)+mu; kld reduce ---------------
__global__ __launch_bounds__(256) void enc_kld(const float* __restrict__ mu,
    const float* __restrict__ lv, const float* __restrict__ eps,
    float* __restrict__ enc, float* __restrict__ kld)
{
  const int idx = blockIdx.x * 256 + threadIdx.x;
  const float m = mu[idx], l = lv[idx];
  enc[idx] = eps[idx] * expf(0.5f * l) + m;
  float term = 1.0f + l - m * m - expf(l);
  __shared__ float red[256];
  red[threadIdx.x] = term;
  __syncthreads();
  for (int s = 128; s > 0; s >>= 1) {
    if (threadIdx.x < s) red[threadIdx.x] += red[threadIdx.x + s];
    __syncthreads();
  }
  if (threadIdx.x == 0) atomicAdd(kld, -0.5f * red[0] / (float)kB);
}

// ---------------- W_comb = w_ih0 @ d_fc2w (bf16 out); b_comb; gvec0 ----------
__global__ __launch_bounds__(256) void prep_comb(const float* __restrict__ wih0,
    const float* __restrict__ bih0, const float* __restrict__ fc2w,
    const float* __restrict__ fc2b, unsigned short* __restrict__ Wcb,
    float* __restrict__ bc, float* __restrict__ g0)
{
  const int idx = blockIdx.x * 256 + threadIdx.x;   // < 1536*512
  const int n = idx >> 9, j = idx & 511;
  float s = 0.f;
#pragma unroll
  for (int v = 0; v < kV; ++v) s = fmaf(wih0[n * kV + v], fc2w[v * kH + j], s);
  Wcb[idx] = f2bf(s);
  if (j == 0) {
    float sb = 0.f;
    for (int v = 0; v < kV; ++v) sb = fmaf(wih0[n * kV + v], fc2b[v], sb);
    bc[n] = bih0[n] + sb;
  }
  if (j == 1) g0[n] = wih0[n * kV + 41] + bih0[n];
}

__global__ __launch_bounds__(256) void conv_bf16(const float* __restrict__ s,
                                                 unsigned short* __restrict__ d, int n)
{
  const int i = blockIdx.x * 256 + threadIdx.x;
  if (i < n) d[i] = f2bf(s[i]);
}

__global__ __launch_bounds__(256) void conv_fc2w_pad(const float* __restrict__ fc2w,
                                                     unsigned short* __restrict__ d)
{
  const int i = blockIdx.x * 256 + threadIdx.x;   // < 48*512
  if (i < 48 * kH) {
    const int r = i >> 9, k = i & 511;
    d[i] = (r < kV) ? f2bf(fc2w[r * kH + k]) : 0;
  }
}

// ---------------- persistent MFMA GRU, LDS-resident weights ------------------
// 256 blocks x 1024 threads. jg = bid>>2 (64 groups of 8 js), mg = bid&3 (128 b).
// LDS: w[96][520] bf16 (T0: [Wc_g j8 | whh1_g j8] x3g; T1: whh0 3x8; B: wih1 3x8)
//      + zpad + CsA[3][8mt][16n][20m] f32 + CsB[3][8mt][8n][20m] f32.
__global__ __launch_bounds__(1024) void gru_mfma(
    const unsigned short* __restrict__ Wcb, const unsigned short* __restrict__ whh0b,
    const unsigned short* __restrict__ wih1b, const unsigned short* __restrict__ whh1b,
    const unsigned short* __restrict__ fc2wb,
    const float* __restrict__ bc, const float* __restrict__ g0,
    const float* __restrict__ bhh0, const float* __restrict__ bih1,
    const float* __restrict__ bhh1, const float* __restrict__ fc2b,
    const float* __restrict__ latg,
    unsigned short* h0A, unsigned short* h0B,
    unsigned short* h1A, unsigned short* h1B,
    float* __restrict__ out)
{
  extern __shared__ char smem[];
  unsigned short* w = (unsigned short*)smem;
  float* CsA = (float*)(smem + kCsAByte);
  float* CsB = CsA + 7680;

  const int tid = threadIdx.x;
  const int wave = tid >> 6;
  const int lane = tid & 63;
  const int quad = lane >> 4;
  const int flr  = lane & 15;
  const int bid = blockIdx.x;
  const int jg = bid >> 2, mg = bid & 3;
  const int jbase = jg * 8;
  const int m0 = mg * 128;

  // ---- one-time weight staging into LDS ----
  for (int c = tid; c < kWRows * 64; c += 1024) {
    const int row = c >> 6;
    const int k8 = (c & 63) << 3;
    const unsigned short* src;
    int srow;
    if (row < 48) {
      const int g = row >> 4, n = row & 15;
      srow = g * kH + jbase + (n & 7);
      src = (n < 8) ? Wcb : whh1b;
    } else if (row < 72) {
      const int rr = row - 48;
      srow = (rr >> 3) * kH + jbase + (rr & 7);
      src = whh0b;
    } else {
      const int rr = row - 72;
      srow = (rr >> 3) * kH + jbase + (rr & 7);
      src = wih1b;
    }
    *(uint4*)&w[row * kWPitch + k8] = *(const uint4*)&src[(size_t)srow * kH + k8];
  }
  if (tid < 32) w[kZPad + tid] = 0;

  // step-invariant LDS B-frag offsets (bf16 units)
  int boffA[3], boffB[3];
  {
    const int q8 = quad * 8;
    if ((wave & 1) == 0) {
#pragma unroll
      for (int g = 0; g < 3; ++g) boffA[g] = (g * 16 + flr) * kWPitch + q8;
    } else {
#pragma unroll
      for (int g = 0; g < 3; ++g)
        boffA[g] = (flr < 8) ? (48 + g * 8 + flr) * kWPitch + q8 : kZPad + q8;
    }
#pragma unroll
    for (int g = 0; g < 3; ++g)
      boffB[g] = (flr < 8) ? (72 + g * 8 + flr) * kWPitch + q8 : kZPad + q8;
  }

  // gate-math mapping: thread -> (gm = local batch 0..127, jl = local j 0..7)
  const int gm = tid >> 3;
  const int jl = tid & 7;
  const int gmt = gm >> 4, gml = gm & 15;
  const int j = jbase + jl;
  const int cA0 = (gmt * 16 + jl) * 20 + gml;       // + g*2560
  const int cA1 = (gmt * 16 + jl + 8) * 20 + gml;   // gh1 rows
  const int cB0 = (gmt * 8 + jl) * 20 + gml;        // + g*1280

  const float b_g0r = g0[j], b_g0z = g0[kH + j], b_g0n = g0[2 * kH + j];
  const float b_bcr = bc[j], b_bcz = bc[kH + j], b_bcn = bc[2 * kH + j];
  const float bh0r = bhh0[j], bh0z = bhh0[kH + j], bh0n = bhh0[2 * kH + j];
  const float bi1r = bih1[j], bi1z = bih1[kH + j], bi1n = bih1[2 * kH + j];
  const float bh1r = bhh1[j], bh1z = bhh1[kH + j], bh1n = bhh1[2 * kH + j];

  float hp0 = latg[(size_t)(m0 + gm) * kH + j];
  float hp1 = 0.f;

  const bool isProj = (jg < 3) && (wave >= 8);
  const int pv = jg * 16 + flr;
  const float fbv = (isProj && pv < kV) ? fc2b[pv] : 0.f;

  cg::grid_group grid = cg::this_grid();
  __syncthreads();

  const unsigned short* h0c = h0A; unsigned short* h0n_ = h0B;
  const unsigned short* h1c = h1A; unsigned short* h1n_ = h1B;
  const f32x4 zf = {0.f, 0.f, 0.f, 0.f};

  for (int t = 0; t < kSEQ; ++t) {
    // ---------- phase A: T0 (gi0|gh1, A=h1c) & T1 (gh0, A=h0c); proj ----------
    if (wave < 8) {
      const unsigned short* Abase = (wave & 1) ? h0c : h1c;
      const unsigned short* ap = Abase + (size_t)(m0 + (wave >> 1) * 32 + flr) * kH + quad * 8;
      f32x4 acc[3][2];
#pragma unroll
      for (int g = 0; g < 3; ++g) { acc[g][0] = zf; acc[g][1] = zf; }
#pragma unroll 4
      for (int kf = 0; kf < 16; ++kf) {
        const int ko = kf * 32;
        const bf16x8 a0 = *(const bf16x8*)(ap + ko);
        const bf16x8 a1 = *(const bf16x8*)(ap + 16 * kH + ko);
#pragma unroll
        for (int g = 0; g < 3; ++g) {
          const bf16x8 b = *(const bf16x8*)&w[boffA[g] + ko];
          acc[g][0] = __builtin_amdgcn_mfma_f32_16x16x32_bf16(a0, b, acc[g][0], 0, 0, 0);
          acc[g][1] = __builtin_amdgcn_mfma_f32_16x16x32_bf16(a1, b, acc[g][1], 0, 0, 0);
        }
      }
      const int mtb = (wave >> 1) * 2;
      if ((wave & 1) == 0) {
#pragma unroll
        for (int g = 0; g < 3; ++g)
#pragma unroll
          for (int p = 0; p < 2; ++p)
            *(f32x4*)&CsA[((g * 8 + mtb + p) * 16 + flr) * 20 + quad * 4] = acc[g][p];
      } else if (flr < 8) {
#pragma unroll
        for (int g = 0; g < 3; ++g)
#pragma unroll
          for (int p = 0; p < 2; ++p)
            *(f32x4*)&CsB[((g * 8 + mtb + p) * 8 + flr) * 20 + quad * 4] = acc[g][p];
      }
    } else if (isProj && t > 0) {
      const int mtP = wave - 8;
      const unsigned short* ap = h1c + (size_t)(m0 + mtP * 16 + flr) * kH + quad * 8;
      const unsigned short* bp = fc2wb + (size_t)(jg * 16 + flr) * kH + quad * 8;
      f32x4 pa = zf;
#pragma unroll 4
      for (int kf = 0; kf < 16; ++kf) {
        const int ko = kf * 32;
        pa = __builtin_amdgcn_mfma_f32_16x16x32_bf16(
            *(const bf16x8*)(ap + ko), *(const bf16x8*)(bp + ko), pa, 0, 0, 0);
      }
      if (pv < kV) {
#pragma unroll
        for (int r = 0; r < 4; ++r)
          out[(size_t)(m0 + mtP * 16 + quad * 4 + r) * (kSEQ * kV)
              + (size_t)(t - 1) * kV + pv] = pa[r] + fbv;
      }
    }
    __syncthreads();
    // ---------- gate L0 ----------
    {
      const float br = (t == 0) ? b_g0r : b_bcr;
      const float bz = (t == 0) ? b_g0z : b_bcz;
      const float bn = (t == 0) ? b_g0n : b_bcn;
      const float gir = CsA[cA0] + br;
      const float giz = CsA[cA0 + 2560] + bz;
      const float gin = CsA[cA0 + 5120] + bn;
      const float ghr = CsB[cB0] + bh0r;
      const float ghz = CsB[cB0 + 1280] + bh0z;
      const float ghn = CsB[cB0 + 2560] + bh0n;
      const float r = sigm(gir + ghr);
      const float z = sigm(giz + ghz);
      const float n = tanhf(gin + r * ghn);
      const float h = (1.f - z) * n + z * hp0;
      hp0 = h;
      h0n_[(size_t)(m0 + gm) * kH + j] = f2bf(h);
    }
    grid.sync();
    // ---------- phase B: gi1 (A=h0n) ----------
    if (wave < 4) {
      const unsigned short* ap = h0n_ + (size_t)(m0 + wave * 32 + flr) * kH + quad * 8;
      f32x4 acc[3][2];
#pragma unroll
      for (int g = 0; g < 3; ++g) { acc[g][0] = zf; acc[g][1] = zf; }
#pragma unroll 4
      for (int kf = 0; kf < 16; ++kf) {
        const int ko = kf * 32;
        const bf16x8 a0 = *(const bf16x8*)(ap + ko);
        const bf16x8 a1 = *(const bf16x8*)(ap + 16 * kH + ko);
#pragma unroll
        for (int g = 0; g < 3; ++g) {
          const bf16x8 b = *(const bf16x8*)&w[boffB[g] + ko];
          acc[g][0] = __builtin_amdgcn_mfma_f32_16x16x32_bf16(a0, b, acc[g][0], 0, 0, 0);
          acc[g][1] = __builtin_amdgcn_mfma_f32_16x16x32_bf16(a1, b, acc[g][1], 0, 0, 0);
        }
      }
      if (flr < 8) {
        const int mtb = wave * 2;
#pragma unroll
        for (int g = 0; g < 3; ++g)
#pragma unroll
          for (int p = 0; p < 2; ++p)
            *(f32x4*)&CsB[((g * 8 + mtb + p) * 8 + flr) * 20 + quad * 4] = acc[g][p];
      }
    }
    __syncthreads();
    // ---------- gate L1 ----------
    {
      const float gir = CsB[cB0] + bi1r;
      const float giz = CsB[cB0 + 1280] + bi1z;
      const float gin = CsB[cB0 + 2560] + bi1n;
      const float ghr = CsA[cA1] + bh1r;
      const float ghz = CsA[cA1 + 2560] + bh1z;
      const float ghn = CsA[cA1 + 5120] + bh1n;
      const float r = sigm(gir + ghr);
      const float z = sigm(giz + ghz);
      const float n = tanhf(gin + r * ghn);
      const float h = (1.f - z) * n + z * hp1;
      hp1 = h;
      h1n_[(size_t)(m0 + gm) * kH + j] = f2bf(h);
    }
    grid.sync();
    {
      const unsigned short* tc;
      tc = h0c; h0c = h0n_; h0n_ = (unsigned short*)tc;
      tc = h1c; h1c = h1n_; h1n_ = (unsigned short*)tc;
    }
  }
  // ---------- tail projection: out[127] ----------
  if (isProj) {
    const int mtP = wave - 8;
    const unsigned short* ap = h1c + (size_t)(m0 + mtP * 16 + flr) * kH + quad * 8;
    const unsigned short* bp = fc2wb + (size_t)(jg * 16 + flr) * kH + quad * 8;
    f32x4 pa = zf;
#pragma unroll 4
    for (int kf = 0; kf < 16; ++kf) {
      const int ko = kf * 32;
      pa = __builtin_amdgcn_mfma_f32_16x16x32_bf16(
          *(const bf16x8*)(ap + ko), *(const bf16x8*)(bp + ko), pa, 0, 0, 0);
    }
    if (pv < kV) {
#pragma unroll
      for (int r = 0; r < 4; ++r)
        out[(size_t)(m0 + mtP * 16 + quad * 4 + r) * (kSEQ * kV)
            + (size_t)(kSEQ - 1) * kV + pv] = pa[r] + fbv;
    }
  }
}

extern "C" void kernel_launch(void* const* d_in, const int* in_sizes, int n_in,
                              void* d_out, int out_size, void* d_ws, size_t ws_size,
                              hipStream_t stream) {
  const float* X    = (const float*)d_in[0];
  const float* eps  = (const float*)d_in[2];
  const float* e1w  = (const float*)d_in[3];  const float* e1b  = (const float*)d_in[4];
  const float* e2w  = (const float*)d_in[5];  const float* e2b  = (const float*)d_in[6];
  const float* e3w  = (const float*)d_in[7];  const float* e3b  = (const float*)d_in[8];
  const float* e41w = (const float*)d_in[9];  const float* e41b = (const float*)d_in[10];
  const float* e42w = (const float*)d_in[11]; const float* e42b = (const float*)d_in[12];
  const float* fc1w = (const float*)d_in[13]; const float* fc1b = (const float*)d_in[14];
  const float* fc2w = (const float*)d_in[15]; const float* fc2b = (const float*)d_in[16];
  const float* wih0 = (const float*)d_in[17]; const float* bih0 = (const float*)d_in[18];
  const float* whh0 = (const float*)d_in[19]; const float* bhh0 = (const float*)d_in[20];
  const float* wih1 = (const float*)d_in[21]; const float* bih1 = (const float*)d_in[22];
  const float* whh1 = (const float*)d_in[23]; const float* bhh1 = (const float*)d_in[24];
  float* out = (float*)d_out;

  float* ws = (float*)d_ws;
  float* eh1 = ws;
  unsigned short* Wcb   = (unsigned short*)(ws + 0);        // 786432 us
  unsigned short* whh0b = (unsigned short*)(ws + 393216);   // 786432 us
  unsigned short* fc2wb = (unsigned short*)(ws + 786432);   // 24576 us
  float* eh2 = ws + 1048576;
  unsigned short* wih1b = (unsigned short*)(ws + 1048576);  // 786432 us
  unsigned short* whh1b = (unsigned short*)(ws + 1441792);  // 786432 us
  float* eh3 = ws + 1572864;
  float* latg = ws + 1835008;                               // 262144 f
  unsigned short* h0a = (unsigned short*)(ws + 2097152);
  unsigned short* h0b = (unsigned short*)(ws + 2228224);
  unsigned short* h1a = (unsigned short*)(ws + 2359296);
  unsigned short* h1b = (unsigned short*)(ws + 2490368);
  float* mu  = ws + 2621440;
  float* lv  = ws + 2654208;
  float* enc = ws + 2686976;
  float* bc  = ws + 2719744;
  float* g0  = ws + 2721280;

  const size_t dec_elems = (size_t)kB * kSEQ * kV;

  // ---- encoder ----
  gemm_bias<true ><<<dim3(32, 8), 256, 0, stream>>>(X,   e1w, e1b, eh1, kB, 2048, 4096);
  gemm_bias<true ><<<dim3(16, 8), 256, 0, stream>>>(eh1, e2w, e2b, eh2, kB, 1024, 2048);
  gemm_bias<true ><<<dim3( 8, 8), 256, 0, stream>>>(eh2, e3w, e3b, eh3, kB,  512, 1024);
  gemm_bias<false><<<dim3( 1, 8), 256, 0, stream>>>(eh3, e41w, e41b, mu, kB,   64,  512);
  gemm_bias<false><<<dim3( 1, 8), 256, 0, stream>>>(eh3, e42w, e42b, lv, kB,   64,  512);
  hipMemsetAsync(out + dec_elems, 0, sizeof(float), stream);
  enc_kld<<<128, 256, 0, stream>>>(mu, lv, eps, enc, out + dec_elems);
  gemm_bias<false><<<dim3(8, 8), 256, 0, stream>>>(enc, fc1w, fc1b, latg, kB, kH, kENC);

  // ---- weight prep (bf16) ----
  prep_comb<<<3072, 256, 0, stream>>>(wih0, bih0, fc2w, fc2b, Wcb, bc, g0);
  conv_bf16<<<3072, 256, 0, stream>>>(whh0, whh0b, 1536 * kH);
  conv_bf16<<<3072, 256, 0, stream>>>(wih1, wih1b, 1536 * kH);
  conv_bf16<<<3072, 256, 0, stream>>>(whh1, whh1b, 1536 * kH);
  conv_fc2w_pad<<<96, 256, 0, stream>>>(fc2w, fc2wb);
  conv_bf16<<<1024, 256, 0, stream>>>(latg, h0a, kB * kH);
  hipMemsetAsync(h1a, 0, (size_t)kB * kH * sizeof(unsigned short), stream);

  // ---- persistent MFMA GRU decoder, LDS-resident weights ----
  hipFuncSetAttribute((const void*)gru_mfma,
                      hipFuncAttributeMaxDynamicSharedMemorySize, kLdsBytes);
  void* args[] = { (void*)&Wcb, (void*)&whh0b, (void*)&wih1b, (void*)&whh1b,
                   (void*)&fc2wb, (void*)&bc, (void*)&g0, (void*)&bhh0,
                   (void*)&bih1, (void*)&bhh1, (void*)&fc2b, (void*)&latg,
                   (void*)&h0a, (void*)&h0b, (void*)&h1a, (void*)&h1b,
                   (void*)&out };
  hipLaunchCooperativeKernel((void*)gru_mfma, dim3(256), dim3(1024), args,
                             kLdsBytes, stream);
}

// Round 5
// 6002.397 us; speedup vs baseline: 4.0966x; 1.7961x over previous
//
#include <hip/hip_runtime.h>
#include <math.h>

constexpr int kB = 512, kENC = 64, kH = 512, kV = 42, kSEQ = 128;
constexpr int kWPitch = 520;                    // bf16 LDS row pitch (bank-skewed)
constexpr int kWRows  = 96;                     // 48 T0 (Wc|whh1) + 24 whh0 + 24 wih1
constexpr int kZPad   = kWRows * kWPitch;       // 49920: 32 bf16 zeros
constexpr int kCsAByte = (kZPad + 32) * 2;      // 99904
constexpr int kLdsBytes = kCsAByte + 30720 + 15360;  // 145984

typedef __attribute__((ext_vector_type(8))) short bf16x8;
typedef __attribute__((ext_vector_type(4))) float f32x4;
typedef unsigned long long u64;

__device__ __forceinline__ unsigned short f2bf(float x) {
  union { float f; unsigned u; } c; c.f = x;
  unsigned r = c.u + 0x7FFFu + ((c.u >> 16) & 1u);
  return (unsigned short)(r >> 16);
}
__device__ __forceinline__ float sigm(float x) { return 1.f / (1.f + expf(-x)); }

// agent-scope (LLC-coherent, L1/L2-bypass) h-state access
__device__ __forceinline__ bf16x8 ld_h16(const unsigned short* p) {
  union { bf16x8 v; u64 q[2]; } u;
  u.q[0] = __hip_atomic_load((const u64*)p,     __ATOMIC_RELAXED, __HIP_MEMORY_SCOPE_AGENT);
  u.q[1] = __hip_atomic_load((const u64*)p + 1, __ATOMIC_RELAXED, __HIP_MEMORY_SCOPE_AGENT);
  return u.v;
}
__device__ __forceinline__ void st_h8(unsigned short* p, u64 v) {
  __hip_atomic_store((u64*)p, v, __ATOMIC_RELAXED, __HIP_MEMORY_SCOPE_AGENT);
}

// two-level device barrier: 8 group counters + top + epoch flag, all in LLC.
// Requires: all cross-block data written with agent-scope stores (drained by
// the __syncthreads vmcnt(0) before arrival) — no L2 flush/inv needed.
__device__ __forceinline__ void dev_barrier(unsigned* bar, unsigned ev, int g) {
  __syncthreads();
  if (threadIdx.x == 0) {
    const unsigned o = __hip_atomic_fetch_add(&bar[g * 64], 1u,
        __ATOMIC_RELAXED, __HIP_MEMORY_SCOPE_AGENT);
    if (o == ev * 32u - 1u) {
      const unsigned o2 = __hip_atomic_fetch_add(&bar[512], 1u,
          __ATOMIC_RELAXED, __HIP_MEMORY_SCOPE_AGENT);
      if (o2 == ev * 8u - 1u)
        __hip_atomic_store(&bar[576], ev, __ATOMIC_RELEASE, __HIP_MEMORY_SCOPE_AGENT);
    }
    while (__hip_atomic_load(&bar[576], __ATOMIC_RELAXED,
                             __HIP_MEMORY_SCOPE_AGENT) < ev)
      __builtin_amdgcn_s_sleep(2);
    (void)__hip_atomic_load(&bar[576], __ATOMIC_ACQUIRE, __HIP_MEMORY_SCOPE_AGENT);
  }
  __syncthreads();
}

// ---------------- generic SGEMM: C[M,N] = act(A[M,K] @ W[N,K]^T + bias[N]) ----
template<bool RELU>
__global__ __launch_bounds__(256) void gemm_bias(const float* __restrict__ A,
    const float* __restrict__ W, const float* __restrict__ bias,
    float* __restrict__ C, int M, int N, int K)
{
  __shared__ float As[16][68];
  __shared__ float Bs[16][68];
  const int tid = threadIdx.x;
  const int n0 = blockIdx.x * 64;
  const int m0 = blockIdx.y * 64;
  const int tx = tid & 15;
  const int ty = tid >> 4;
  const int lr = tid >> 2;
  const int lk = (tid & 3) << 2;
  float acc[4][4] = {};
  for (int kc = 0; kc < K; kc += 16) {
    const float4 va = *(const float4*)(A + (size_t)(m0 + lr) * K + kc + lk);
    const float4 vb = *(const float4*)(W + (size_t)(n0 + lr) * K + kc + lk);
    __syncthreads();
    As[lk+0][lr] = va.x; As[lk+1][lr] = va.y; As[lk+2][lr] = va.z; As[lk+3][lr] = va.w;
    Bs[lk+0][lr] = vb.x; Bs[lk+1][lr] = vb.y; Bs[lk+2][lr] = vb.z; Bs[lk+3][lr] = vb.w;
    __syncthreads();
#pragma unroll
    for (int k = 0; k < 16; ++k) {
      const float4 a = *(const float4*)&As[k][ty << 2];
      const float4 b = *(const float4*)&Bs[k][tx << 2];
      const float av[4] = {a.x, a.y, a.z, a.w};
      const float bv[4] = {b.x, b.y, b.z, b.w};
#pragma unroll
      for (int i = 0; i < 4; ++i)
#pragma unroll
        for (int jj = 0; jj < 4; ++jj) acc[i][jj] = fmaf(av[i], bv[jj], acc[i][jj]);
    }
  }
  const int cn = n0 + (tx << 2);
  const float4 b4 = *(const float4*)&bias[cn];
  const float bvv[4] = {b4.x, b4.y, b4.z, b4.w};
#pragma unroll
  for (int i = 0; i < 4; ++i) {
    float4 o;
    float* op = &o.x;
#pragma unroll
    for (int jj = 0; jj < 4; ++jj) {
      float v = acc[i][jj] + bvv[jj];
      if (RELU) v = fmaxf(v, 0.f);
      op[jj] = v;
    }
    *(float4*)(C + (size_t)(m0 + (ty << 2) + i) * N + cn) = o;
  }
}

// ---------------- encoded = eps*exp(0.5*logvar)+mu; kld reduce ---------------
__global__ __launch_bounds__(256) void enc_kld(const float* __restrict__ mu,
    const float* __restrict__ lv, const float* __restrict__ eps,
    float* __restrict__ enc, float* __restrict__ kld)
{
  const int idx = blockIdx.x * 256 + threadIdx.x;
  const float m = mu[idx], l = lv[idx];
  enc[idx] = eps[idx] * expf(0.5f * l) + m;
  float term = 1.0f + l - m * m - expf(l);
  __shared__ float red[256];
  red[threadIdx.x] = term;
  __syncthreads();
  for (int s = 128; s > 0; s >>= 1) {
    if (threadIdx.x < s) red[threadIdx.x] += red[threadIdx.x + s];
    __syncthreads();
  }
  if (threadIdx.x == 0) atomicAdd(kld, -0.5f * red[0] / (float)kB);
}

// ---------------- W_comb = w_ih0 @ d_fc2w (bf16 out); b_comb; gvec0 ----------
__global__ __launch_bounds__(256) void prep_comb(const float* __restrict__ wih0,
    const float* __restrict__ bih0, const float* __restrict__ fc2w,
    const float* __restrict__ fc2b, unsigned short* __restrict__ Wcb,
    float* __restrict__ bc, float* __restrict__ g0)
{
  const int idx = blockIdx.x * 256 + threadIdx.x;   // < 1536*512
  const int n = idx >> 9, j = idx & 511;
  float s = 0.f;
#pragma unroll
  for (int v = 0; v < kV; ++v) s = fmaf(wih0[n * kV + v], fc2w[v * kH + j], s);
  Wcb[idx] = f2bf(s);
  if (j == 0) {
    float sb = 0.f;
    for (int v = 0; v < kV; ++v) sb = fmaf(wih0[n * kV + v], fc2b[v], sb);
    bc[n] = bih0[n] + sb;
  }
  if (j == 1) g0[n] = wih0[n * kV + 41] + bih0[n];
}

__global__ __launch_bounds__(256) void conv_bf16(const float* __restrict__ s,
                                                 unsigned short* __restrict__ d, int n)
{
  const int i = blockIdx.x * 256 + threadIdx.x;
  if (i < n) d[i] = f2bf(s[i]);
}

__global__ __launch_bounds__(256) void conv_fc2w_pad(const float* __restrict__ fc2w,
                                                     unsigned short* __restrict__ d)
{
  const int i = blockIdx.x * 256 + threadIdx.x;   // < 48*512
  if (i < 48 * kH) {
    const int r = i >> 9, k = i & 511;
    d[i] = (r < kV) ? f2bf(fc2w[r * kH + k]) : 0;
  }
}

// ---------------- persistent MFMA GRU, LDS weights + custom LLC barrier ------
__global__ __launch_bounds__(1024) void gru_mfma(
    const unsigned short* __restrict__ Wcb, const unsigned short* __restrict__ whh0b,
    const unsigned short* __restrict__ wih1b, const unsigned short* __restrict__ whh1b,
    const unsigned short* __restrict__ fc2wb,
    const float* __restrict__ bc, const float* __restrict__ g0,
    const float* __restrict__ bhh0, const float* __restrict__ bih1,
    const float* __restrict__ bhh1, const float* __restrict__ fc2b,
    const float* __restrict__ latg,
    unsigned short* h0A, unsigned short* h0B,
    unsigned short* h1A, unsigned short* h1B,
    float* __restrict__ out, unsigned* bar)
{
  extern __shared__ char smem[];
  unsigned short* w = (unsigned short*)smem;
  float* CsA = (float*)(smem + kCsAByte);
  float* CsB = CsA + 7680;

  const int tid = threadIdx.x;
  const int wave = tid >> 6;
  const int lane = tid & 63;
  const int quad = lane >> 4;
  const int flr  = lane & 15;
  const int bid = blockIdx.x;
  const int jg = bid >> 2, mg = bid & 3;
  const int jbase = jg * 8;
  const int m0 = mg * 128;
  const int barg = bid & 7;

  // ---- one-time weight staging into LDS ----
  for (int c = tid; c < kWRows * 64; c += 1024) {
    const int row = c >> 6;
    const int k8 = (c & 63) << 3;
    const unsigned short* src;
    int srow;
    if (row < 48) {
      const int g = row >> 4, n = row & 15;
      srow = g * kH + jbase + (n & 7);
      src = (n < 8) ? Wcb : whh1b;
    } else if (row < 72) {
      const int rr = row - 48;
      srow = (rr >> 3) * kH + jbase + (rr & 7);
      src = whh0b;
    } else {
      const int rr = row - 72;
      srow = (rr >> 3) * kH + jbase + (rr & 7);
      src = wih1b;
    }
    *(uint4*)&w[row * kWPitch + k8] = *(const uint4*)&src[(size_t)srow * kH + k8];
  }
  if (tid < 32) w[kZPad + tid] = 0;

  // step-invariant LDS B-frag offsets (bf16 units)
  int boffA[3], boffB[3];
  {
    const int q8 = quad * 8;
    if ((wave & 1) == 0) {
#pragma unroll
      for (int g = 0; g < 3; ++g) boffA[g] = (g * 16 + flr) * kWPitch + q8;
    } else {
#pragma unroll
      for (int g = 0; g < 3; ++g)
        boffA[g] = (flr < 8) ? (48 + g * 8 + flr) * kWPitch + q8 : kZPad + q8;
    }
#pragma unroll
    for (int g = 0; g < 3; ++g)
      boffB[g] = (flr < 8) ? (72 + g * 8 + flr) * kWPitch + q8 : kZPad + q8;
  }

  // gate-math mapping: tid<256 -> gm = tid>>1 (batch 0..127), 4 js at jq*4
  const int gm = tid >> 1;
  const int jl0 = (tid & 1) << 2;
  const int gmt = gm >> 4, gml = gm & 15;
  const int gj = jbase + jl0;                       // absolute j of first lane

  float hp0[4], hp1[4];
  if (tid < 256) {
    const float4 l4 = *(const float4*)(latg + (size_t)(m0 + gm) * kH + gj);
    hp0[0] = l4.x; hp0[1] = l4.y; hp0[2] = l4.z; hp0[3] = l4.w;
    hp1[0] = hp1[1] = hp1[2] = hp1[3] = 0.f;
  }

  const bool isProj = (jg < 3) && (wave >= 8);
  const int pv = jg * 16 + flr;
  const float fbv = (isProj && pv < kV) ? fc2b[pv] : 0.f;

  __syncthreads();

  const unsigned short* h0c = h0A; unsigned short* h0n_ = h0B;
  const unsigned short* h1c = h1A; unsigned short* h1n_ = h1B;
  const f32x4 zf = {0.f, 0.f, 0.f, 0.f};

  for (int t = 0; t < kSEQ; ++t) {
    // ---------- phase A: T0 (gi0|gh1, A=h1c) & T1 (gh0, A=h0c); proj ----------
    if (wave < 8) {
      const unsigned short* Abase = (wave & 1) ? h0c : h1c;
      const unsigned short* ap = Abase + (size_t)(m0 + (wave >> 1) * 32 + flr) * kH + quad * 8;
      f32x4 acc[3][2];
#pragma unroll
      for (int g = 0; g < 3; ++g) { acc[g][0] = zf; acc[g][1] = zf; }
#pragma unroll 4
      for (int kf = 0; kf < 16; ++kf) {
        const int ko = kf * 32;
        const bf16x8 a0 = ld_h16(ap + ko);
        const bf16x8 a1 = ld_h16(ap + 16 * kH + ko);
#pragma unroll
        for (int g = 0; g < 3; ++g) {
          const bf16x8 b = *(const bf16x8*)&w[boffA[g] + ko];
          acc[g][0] = __builtin_amdgcn_mfma_f32_16x16x32_bf16(a0, b, acc[g][0], 0, 0, 0);
          acc[g][1] = __builtin_amdgcn_mfma_f32_16x16x32_bf16(a1, b, acc[g][1], 0, 0, 0);
        }
      }
      const int mtb = (wave >> 1) * 2;
      if ((wave & 1) == 0) {
#pragma unroll
        for (int g = 0; g < 3; ++g)
#pragma unroll
          for (int p = 0; p < 2; ++p)
            *(f32x4*)&CsA[((g * 8 + mtb + p) * 16 + flr) * 20 + quad * 4] = acc[g][p];
      } else if (flr < 8) {
#pragma unroll
        for (int g = 0; g < 3; ++g)
#pragma unroll
          for (int p = 0; p < 2; ++p)
            *(f32x4*)&CsB[((g * 8 + mtb + p) * 8 + flr) * 20 + quad * 4] = acc[g][p];
      }
    } else if (isProj && t > 0) {
      const int mtP = wave - 8;
      const unsigned short* ap = h1c + (size_t)(m0 + mtP * 16 + flr) * kH + quad * 8;
      const unsigned short* bp = fc2wb + (size_t)(jg * 16 + flr) * kH + quad * 8;
      f32x4 pa = zf;
#pragma unroll 4
      for (int kf = 0; kf < 16; ++kf) {
        const int ko = kf * 32;
        pa = __builtin_amdgcn_mfma_f32_16x16x32_bf16(
            ld_h16(ap + ko), *(const bf16x8*)(bp + ko), pa, 0, 0, 0);
      }
      if (pv < kV) {
#pragma unroll
        for (int r = 0; r < 4; ++r)
          out[(size_t)(m0 + mtP * 16 + quad * 4 + r) * (kSEQ * kV)
              + (size_t)(t - 1) * kV + pv] = pa[r] + fbv;
      }
    }
    __syncthreads();
    // ---------- gate L0 (256 threads x 4 js) ----------
    if (tid < 256) {
      const float* bi = (t == 0) ? g0 : bc;
      const float4 bir = *(const float4*)(bi + gj);
      const float4 biz = *(const float4*)(bi + kH + gj);
      const float4 bin = *(const float4*)(bi + 2 * kH + gj);
      const float4 bhr = *(const float4*)(bhh0 + gj);
      const float4 bhz = *(const float4*)(bhh0 + kH + gj);
      const float4 bhn = *(const float4*)(bhh0 + 2 * kH + gj);
      u64 pack = 0;
#pragma unroll
      for (int i = 0; i < 4; ++i) {
        const int jl = jl0 + i;
        const float gir = CsA[(gmt * 16 + jl) * 20 + gml] + ((const float*)&bir)[i];
        const float giz = CsA[2560 + (gmt * 16 + jl) * 20 + gml] + ((const float*)&biz)[i];
        const float gin = CsA[5120 + (gmt * 16 + jl) * 20 + gml] + ((const float*)&bin)[i];
        const float ghr = CsB[(gmt * 8 + jl) * 20 + gml] + ((const float*)&bhr)[i];
        const float ghz = CsB[1280 + (gmt * 8 + jl) * 20 + gml] + ((const float*)&bhz)[i];
        const float ghn = CsB[2560 + (gmt * 8 + jl) * 20 + gml] + ((const float*)&bhn)[i];
        const float r = sigm(gir + ghr);
        const float z = sigm(giz + ghz);
        const float n = tanhf(gin + r * ghn);
        const float h = (1.f - z) * n + z * hp0[i];
        hp0[i] = h;
        pack |= (u64)f2bf(h) << (16 * i);
      }
      st_h8(h0n_ + (size_t)(m0 + gm) * kH + gj, pack);
    }
    dev_barrier(bar, (unsigned)(2 * t + 1), barg);
    // ---------- phase B: gi1 (A=h0n) ----------
    if (wave < 4) {
      const unsigned short* ap = h0n_ + (size_t)(m0 + wave * 32 + flr) * kH + quad * 8;
      f32x4 acc[3][2];
#pragma unroll
      for (int g = 0; g < 3; ++g) { acc[g][0] = zf; acc[g][1] = zf; }
#pragma unroll 4
      for (int kf = 0; kf < 16; ++kf) {
        const int ko = kf * 32;
        const bf16x8 a0 = ld_h16(ap + ko);
        const bf16x8 a1 = ld_h16(ap + 16 * kH + ko);
#pragma unroll
        for (int g = 0; g < 3; ++g) {
          const bf16x8 b = *(const bf16x8*)&w[boffB[g] + ko];
          acc[g][0] = __builtin_amdgcn_mfma_f32_16x16x32_bf16(a0, b, acc[g][0], 0, 0, 0);
          acc[g][1] = __builtin_amdgcn_mfma_f32_16x16x32_bf16(a1, b, acc[g][1], 0, 0, 0);
        }
      }
      if (flr < 8) {
        const int mtb = wave * 2;
#pragma unroll
        for (int g = 0; g < 3; ++g)
#pragma unroll
          for (int p = 0; p < 2; ++p)
            *(f32x4*)&CsB[((g * 8 + mtb + p) * 8 + flr) * 20 + quad * 4] = acc[g][p];
      }
    }
    __syncthreads();
    // ---------- gate L1 (256 threads x 4 js) ----------
    if (tid < 256) {
      const float4 bir = *(const float4*)(bih1 + gj);
      const float4 biz = *(const float4*)(bih1 + kH + gj);
      const float4 bin = *(const float4*)(bih1 + 2 * kH + gj);
      const float4 bhr = *(const float4*)(bhh1 + gj);
      const float4 bhz = *(const float4*)(bhh1 + kH + gj);
      const float4 bhn = *(const float4*)(bhh1 + 2 * kH + gj);
      u64 pack = 0;
#pragma unroll
      for (int i = 0; i < 4; ++i) {
        const int jl = jl0 + i;
        const float gir = CsB[(gmt * 8 + jl) * 20 + gml] + ((const float*)&bir)[i];
        const float giz = CsB[1280 + (gmt * 8 + jl) * 20 + gml] + ((const float*)&biz)[i];
        const float gin = CsB[2560 + (gmt * 8 + jl) * 20 + gml] + ((const float*)&bin)[i];
        const float ghr = CsA[(gmt * 16 + jl + 8) * 20 + gml] + ((const float*)&bhr)[i];
        const float ghz = CsA[2560 + (gmt * 16 + jl + 8) * 20 + gml] + ((const float*)&bhz)[i];
        const float ghn = CsA[5120 + (gmt * 16 + jl + 8) * 20 + gml] + ((const float*)&bhn)[i];
        const float r = sigm(gir + ghr);
        const float z = sigm(giz + ghz);
        const float n = tanhf(gin + r * ghn);
        const float h = (1.f - z) * n + z * hp1[i];
        hp1[i] = h;
        pack |= (u64)f2bf(h) << (16 * i);
      }
      st_h8(h1n_ + (size_t)(m0 + gm) * kH + gj, pack);
    }
    dev_barrier(bar, (unsigned)(2 * t + 2), barg);
    {
      const unsigned short* tc;
      tc = h0c; h0c = h0n_; h0n_ = (unsigned short*)tc;
      tc = h1c; h1c = h1n_; h1n_ = (unsigned short*)tc;
    }
  }
  // ---------- tail projection: out[127] ----------
  if (isProj) {
    const int mtP = wave - 8;
    const unsigned short* ap = h1c + (size_t)(m0 + mtP * 16 + flr) * kH + quad * 8;
    const unsigned short* bp = fc2wb + (size_t)(jg * 16 + flr) * kH + quad * 8;
    f32x4 pa = zf;
#pragma unroll 4
    for (int kf = 0; kf < 16; ++kf) {
      const int ko = kf * 32;
      pa = __builtin_amdgcn_mfma_f32_16x16x32_bf16(
          ld_h16(ap + ko), *(const bf16x8*)(bp + ko), pa, 0, 0, 0);
    }
    if (pv < kV) {
#pragma unroll
      for (int r = 0; r < 4; ++r)
        out[(size_t)(m0 + mtP * 16 + quad * 4 + r) * (kSEQ * kV)
            + (size_t)(kSEQ - 1) * kV + pv] = pa[r] + fbv;
    }
  }
}

extern "C" void kernel_launch(void* const* d_in, const int* in_sizes, int n_in,
                              void* d_out, int out_size, void* d_ws, size_t ws_size,
                              hipStream_t stream) {
  const float* X    = (const float*)d_in[0];
  const float* eps  = (const float*)d_in[2];
  const float* e1w  = (const float*)d_in[3];  const float* e1b  = (const float*)d_in[4];
  const float* e2w  = (const float*)d_in[5];  const float* e2b  = (const float*)d_in[6];
  const float* e3w  = (const float*)d_in[7];  const float* e3b  = (const float*)d_in[8];
  const float* e41w = (const float*)d_in[9];  const float* e41b = (const float*)d_in[10];
  const float* e42w = (const float*)d_in[11]; const float* e42b = (const float*)d_in[12];
  const float* fc1w = (const float*)d_in[13]; const float* fc1b = (const float*)d_in[14];
  const float* fc2w = (const float*)d_in[15]; const float* fc2b = (const float*)d_in[16];
  const float* wih0 = (const float*)d_in[17]; const float* bih0 = (const float*)d_in[18];
  const float* whh0 = (const float*)d_in[19]; const float* bhh0 = (const float*)d_in[20];
  const float* wih1 = (const float*)d_in[21]; const float* bih1 = (const float*)d_in[22];
  const float* whh1 = (const float*)d_in[23]; const float* bhh1 = (const float*)d_in[24];
  float* out = (float*)d_out;

  float* ws = (float*)d_ws;
  float* eh1 = ws;
  unsigned short* Wcb   = (unsigned short*)(ws + 0);        // 786432 us
  unsigned short* whh0b = (unsigned short*)(ws + 393216);   // 786432 us
  unsigned short* fc2wb = (unsigned short*)(ws + 786432);   // 24576 us
  float* eh2 = ws + 1048576;
  unsigned short* wih1b = (unsigned short*)(ws + 1048576);  // 786432 us
  unsigned short* whh1b = (unsigned short*)(ws + 1441792);  // 786432 us
  float* eh3 = ws + 1572864;
  float* latg = ws + 1835008;                               // 262144 f
  unsigned short* h0a = (unsigned short*)(ws + 2097152);
  unsigned short* h0b = (unsigned short*)(ws + 2228224);
  unsigned short* h1a = (unsigned short*)(ws + 2359296);
  unsigned short* h1b = (unsigned short*)(ws + 2490368);
  float* mu  = ws + 2621440;
  float* lv  = ws + 2654208;
  float* enc = ws + 2686976;
  float* bc  = ws + 2719744;
  float* g0  = ws + 2721280;
  unsigned* bar = (unsigned*)(ws + 2723840);                // 1024 u32

  const size_t dec_elems = (size_t)kB * kSEQ * kV;

  // ---- encoder ----
  gemm_bias<true ><<<dim3(32, 8), 256, 0, stream>>>(X,   e1w, e1b, eh1, kB, 2048, 4096);
  gemm_bias<true ><<<dim3(16, 8), 256, 0, stream>>>(eh1, e2w, e2b, eh2, kB, 1024, 2048);
  gemm_bias<true ><<<dim3( 8, 8), 256, 0, stream>>>(eh2, e3w, e3b, eh3, kB,  512, 1024);
  gemm_bias<false><<<dim3( 1, 8), 256, 0, stream>>>(eh3, e41w, e41b, mu, kB,   64,  512);
  gemm_bias<false><<<dim3( 1, 8), 256, 0, stream>>>(eh3, e42w, e42b, lv, kB,   64,  512);
  hipMemsetAsync(out + dec_elems, 0, sizeof(float), stream);
  enc_kld<<<128, 256, 0, stream>>>(mu, lv, eps, enc, out + dec_elems);
  gemm_bias<false><<<dim3(8, 8), 256, 0, stream>>>(enc, fc1w, fc1b, latg, kB, kH, kENC);

  // ---- weight prep (bf16) + barrier init ----
  prep_comb<<<3072, 256, 0, stream>>>(wih0, bih0, fc2w, fc2b, Wcb, bc, g0);
  conv_bf16<<<3072, 256, 0, stream>>>(whh0, whh0b, 1536 * kH);
  conv_bf16<<<3072, 256, 0, stream>>>(wih1, wih1b, 1536 * kH);
  conv_bf16<<<3072, 256, 0, stream>>>(whh1, whh1b, 1536 * kH);
  conv_fc2w_pad<<<96, 256, 0, stream>>>(fc2w, fc2wb);
  conv_bf16<<<1024, 256, 0, stream>>>(latg, h0a, kB * kH);
  hipMemsetAsync(h1a, 0, (size_t)kB * kH * sizeof(unsigned short), stream);
  hipMemsetAsync(bar, 0, 4096, stream);

  // ---- persistent MFMA GRU decoder ----
  hipFuncSetAttribute((const void*)gru_mfma,
                      hipFuncAttributeMaxDynamicSharedMemorySize, kLdsBytes);
  void* args[] = { (void*)&Wcb, (void*)&whh0b, (void*)&wih1b, (void*)&whh1b,
                   (void*)&fc2wb, (void*)&bc, (void*)&g0, (void*)&bhh0,
                   (void*)&bih1, (void*)&bhh1, (void*)&fc2b, (void*)&latg,
                   (void*)&h0a, (void*)&h0b, (void*)&h1a, (void*)&h1b,
                   (void*)&out, (void*)&bar };
  hipLaunchCooperativeKernel((void*)gru_mfma, dim3(256), dim3(1024), args,
                             kLdsBytes, stream);
}

// Round 6
// 5758.690 us; speedup vs baseline: 4.2700x; 1.0423x over previous
//
#include <hip/hip_runtime.h>
#include <math.h>

constexpr int kB = 512, kENC = 64, kH = 512, kV = 42, kSEQ = 128;
constexpr int kWPitch = 520;                    // bf16 LDS row pitch (bank-skewed)
constexpr int kWRows  = 96;                     // 48 T0 (Wc|whh1) + 24 whh0 + 24 wih1
constexpr int kZPad   = kWRows * kWPitch;       // 49920: 32 bf16 zeros
constexpr int kCsAByte = (kZPad + 32) * 2;      // 99904
constexpr int kLdsBytes = kCsAByte + 30720 + 15360;  // 145984

typedef __attribute__((ext_vector_type(8))) short bf16x8;
typedef __attribute__((ext_vector_type(4))) float f32x4;
typedef unsigned long long u64;

__device__ __forceinline__ unsigned short f2bf(float x) {
  union { float f; unsigned u; } c; c.f = x;
  unsigned r = c.u + 0x7FFFu + ((c.u >> 16) & 1u);
  return (unsigned short)(r >> 16);
}
__device__ __forceinline__ float sigm(float x) { return 1.f / (1.f + expf(-x)); }

// agent-scope (LLC-coherent, L1/L2-bypass) h-state access
__device__ __forceinline__ bf16x8 ld_h16(const unsigned short* p) {
  union { bf16x8 v; u64 q[2]; } u;
  u.q[0] = __hip_atomic_load((const u64*)p,     __ATOMIC_RELAXED, __HIP_MEMORY_SCOPE_AGENT);
  u.q[1] = __hip_atomic_load((const u64*)p + 1, __ATOMIC_RELAXED, __HIP_MEMORY_SCOPE_AGENT);
  return u.v;
}
__device__ __forceinline__ void st_h2(unsigned short* p, unsigned short v) {
  __hip_atomic_store(p, v, __ATOMIC_RELAXED, __HIP_MEMORY_SCOPE_AGENT);
}

// per-mg-group barrier: 64 blocks, 8 sub-counters x 8 blocks + top + flag.
// Cross-block data is agent-scope only -> no L2 maintenance needed.
__device__ __forceinline__ void mg_barrier(unsigned* bar, unsigned ev, int mg, int sub) {
  __syncthreads();
  if (threadIdx.x == 0) {
    const unsigned o = __hip_atomic_fetch_add(&bar[(mg * 8 + sub) * 16], 1u,
        __ATOMIC_RELAXED, __HIP_MEMORY_SCOPE_AGENT);
    if (o == ev * 8u - 1u) {
      const unsigned o2 = __hip_atomic_fetch_add(&bar[(32 + mg) * 16], 1u,
          __ATOMIC_RELAXED, __HIP_MEMORY_SCOPE_AGENT);
      if (o2 == ev * 8u - 1u)
        __hip_atomic_store(&bar[(36 + mg) * 16], ev,
                           __ATOMIC_RELEASE, __HIP_MEMORY_SCOPE_AGENT);
    }
    while (__hip_atomic_load(&bar[(36 + mg) * 16], __ATOMIC_RELAXED,
                             __HIP_MEMORY_SCOPE_AGENT) < ev)
      __builtin_amdgcn_s_sleep(1);
    (void)__hip_atomic_load(&bar[(36 + mg) * 16], __ATOMIC_ACQUIRE,
                            __HIP_MEMORY_SCOPE_AGENT);
  }
  __syncthreads();
}

// ---------------- generic SGEMM: C[M,N] = act(A[M,K] @ W[N,K]^T + bias[N]) ----
template<bool RELU>
__global__ __launch_bounds__(256) void gemm_bias(const float* __restrict__ A,
    const float* __restrict__ W, const float* __restrict__ bias,
    float* __restrict__ C, int M, int N, int K)
{
  __shared__ float As[16][68];
  __shared__ float Bs[16][68];
  const int tid = threadIdx.x;
  const int n0 = blockIdx.x * 64;
  const int m0 = blockIdx.y * 64;
  const int tx = tid & 15;
  const int ty = tid >> 4;
  const int lr = tid >> 2;
  const int lk = (tid & 3) << 2;
  float acc[4][4] = {};
  for (int kc = 0; kc < K; kc += 16) {
    const float4 va = *(const float4*)(A + (size_t)(m0 + lr) * K + kc + lk);
    const float4 vb = *(const float4*)(W + (size_t)(n0 + lr) * K + kc + lk);
    __syncthreads();
    As[lk+0][lr] = va.x; As[lk+1][lr] = va.y; As[lk+2][lr] = va.z; As[lk+3][lr] = va.w;
    Bs[lk+0][lr] = vb.x; Bs[lk+1][lr] = vb.y; Bs[lk+2][lr] = vb.z; Bs[lk+3][lr] = vb.w;
    __syncthreads();
#pragma unroll
    for (int k = 0; k < 16; ++k) {
      const float4 a = *(const float4*)&As[k][ty << 2];
      const float4 b = *(const float4*)&Bs[k][tx << 2];
      const float av[4] = {a.x, a.y, a.z, a.w};
      const float bv[4] = {b.x, b.y, b.z, b.w};
#pragma unroll
      for (int i = 0; i < 4; ++i)
#pragma unroll
        for (int jj = 0; jj < 4; ++jj) acc[i][jj] = fmaf(av[i], bv[jj], acc[i][jj]);
    }
  }
  const int cn = n0 + (tx << 2);
  const float4 b4 = *(const float4*)&bias[cn];
  const float bvv[4] = {b4.x, b4.y, b4.z, b4.w};
#pragma unroll
  for (int i = 0; i < 4; ++i) {
    float4 o;
    float* op = &o.x;
#pragma unroll
    for (int jj = 0; jj < 4; ++jj) {
      float v = acc[i][jj] + bvv[jj];
      if (RELU) v = fmaxf(v, 0.f);
      op[jj] = v;
    }
    *(float4*)(C + (size_t)(m0 + (ty << 2) + i) * N + cn) = o;
  }
}

// ---------------- encoded = eps*exp(0.5*logvar)+mu; kld reduce ---------------
__global__ __launch_bounds__(256) void enc_kld(const float* __restrict__ mu,
    const float* __restrict__ lv, const float* __restrict__ eps,
    float* __restrict__ enc, float* __restrict__ kld)
{
  const int idx = blockIdx.x * 256 + threadIdx.x;
  const float m = mu[idx], l = lv[idx];
  enc[idx] = eps[idx] * expf(0.5f * l) + m;
  float term = 1.0f + l - m * m - expf(l);
  __shared__ float red[256];
  red[threadIdx.x] = term;
  __syncthreads();
  for (int s = 128; s > 0; s >>= 1) {
    if (threadIdx.x < s) red[threadIdx.x] += red[threadIdx.x + s];
    __syncthreads();
  }
  if (threadIdx.x == 0) atomicAdd(kld, -0.5f * red[0] / (float)kB);
}

// ---------------- W_comb = w_ih0 @ d_fc2w (bf16 out); b_comb; gvec0 ----------
__global__ __launch_bounds__(256) void prep_comb(const float* __restrict__ wih0,
    const float* __restrict__ bih0, const float* __restrict__ fc2w,
    const float* __restrict__ fc2b, unsigned short* __restrict__ Wcb,
    float* __restrict__ bc, float* __restrict__ g0)
{
  const int idx = blockIdx.x * 256 + threadIdx.x;   // < 1536*512
  const int n = idx >> 9, j = idx & 511;
  float s = 0.f;
#pragma unroll
  for (int v = 0; v < kV; ++v) s = fmaf(wih0[n * kV + v], fc2w[v * kH + j], s);
  Wcb[idx] = f2bf(s);
  if (j == 0) {
    float sb = 0.f;
    for (int v = 0; v < kV; ++v) sb = fmaf(wih0[n * kV + v], fc2b[v], sb);
    bc[n] = bih0[n] + sb;
  }
  if (j == 1) g0[n] = wih0[n * kV + 41] + bih0[n];
}

__global__ __launch_bounds__(256) void conv_bf16(const float* __restrict__ s,
                                                 unsigned short* __restrict__ d, int n)
{
  const int i = blockIdx.x * 256 + threadIdx.x;
  if (i < n) d[i] = f2bf(s[i]);
}

__global__ __launch_bounds__(256) void conv_fc2w_pad(const float* __restrict__ fc2w,
                                                     unsigned short* __restrict__ d)
{
  const int i = blockIdx.x * 256 + threadIdx.x;   // < 48*512
  if (i < 48 * kH) {
    const int r = i >> 9, k = i & 511;
    d[i] = (r < kV) ? f2bf(fc2w[r * kH + k]) : 0;
  }
}

// ---------------- persistent MFMA GRU, LDS weights + 4 mg-group barriers -----
// 256 blocks x 1024 threads. jg = bid>>2 (64 x 8 js), mg = bid&3 (128 batches).
// Phase A: waves 0-7 T0 (gi0|gh1, A=h1c), waves 8-15 T1 (gh0, A=h0c).
// Phase B: waves 0-7 gi1 (A=h0n); waves 8-15 of jg<3 blocks: out-projection.
// Gate math: all 1024 threads, one (m,j) item each.
__global__ __launch_bounds__(1024) void gru_mfma(
    const unsigned short* __restrict__ Wcb, const unsigned short* __restrict__ whh0b,
    const unsigned short* __restrict__ wih1b, const unsigned short* __restrict__ whh1b,
    const unsigned short* __restrict__ fc2wb,
    const float* __restrict__ bc, const float* __restrict__ g0,
    const float* __restrict__ bhh0, const float* __restrict__ bih1,
    const float* __restrict__ bhh1, const float* __restrict__ fc2b,
    const float* __restrict__ latg,
    unsigned short* h0A, unsigned short* h0B,
    unsigned short* h1A, unsigned short* h1B,
    float* __restrict__ out, unsigned* bar)
{
  extern __shared__ char smem[];
  unsigned short* w = (unsigned short*)smem;
  float* CsA = (float*)(smem + kCsAByte);
  float* CsB = CsA + 7680;

  const int tid = threadIdx.x;
  const int wave = tid >> 6;
  const int lane = tid & 63;
  const int quad = lane >> 4;
  const int flr  = lane & 15;
  const int q8   = quad * 8;
  const int bid = blockIdx.x;
  const int jg = bid >> 2, mg = bid & 3;
  const int jbase = jg * 8;
  const int m0 = mg * 128;
  const int sub = jg & 7;

  // ---- one-time weight staging into LDS ----
  for (int c = tid; c < kWRows * 64; c += 1024) {
    const int row = c >> 6;
    const int k8 = (c & 63) << 3;
    const unsigned short* src;
    int srow;
    if (row < 48) {
      const int g = row >> 4, n = row & 15;
      srow = g * kH + jbase + (n & 7);
      src = (n < 8) ? Wcb : whh1b;
    } else if (row < 72) {
      const int rr = row - 48;
      srow = (rr >> 3) * kH + jbase + (rr & 7);
      src = whh0b;
    } else {
      const int rr = row - 72;
      srow = (rr >> 3) * kH + jbase + (rr & 7);
      src = wih1b;
    }
    *(uint4*)&w[row * kWPitch + k8] = *(const uint4*)&src[(size_t)srow * kH + k8];
  }
  if (tid < 32) w[kZPad + tid] = 0;

  // step-invariant LDS B-frag offsets (bf16 units)
  int boffT0[3], boffT1[3], boffB[3];
#pragma unroll
  for (int g = 0; g < 3; ++g) {
    boffT0[g] = (g * 16 + flr) * kWPitch + q8;
    boffT1[g] = (flr < 8) ? (48 + g * 8 + flr) * kWPitch + q8 : kZPad + q8;
    boffB[g]  = (flr < 8) ? (72 + g * 8 + flr) * kWPitch + q8 : kZPad + q8;
  }

  // gate-math mapping: one item per thread: m = tid>>3 (0..127), jl = tid&7
  const int gm = tid >> 3;
  const int jl = tid & 7;
  const int gmt = gm >> 4, gml = gm & 15;
  const int j = jbase + jl;

  const float bg0r = g0[j], bg0z = g0[kH + j], bg0n = g0[2 * kH + j];
  const float bbcr = bc[j], bbcz = bc[kH + j], bbcn = bc[2 * kH + j];
  const float bh0r = bhh0[j], bh0z = bhh0[kH + j], bh0n = bhh0[2 * kH + j];
  const float bi1r = bih1[j], bi1z = bih1[kH + j], bi1n = bih1[2 * kH + j];
  const float bh1r = bhh1[j], bh1z = bhh1[kH + j], bh1n = bhh1[2 * kH + j];

  float hp0 = latg[(size_t)(m0 + gm) * kH + j];
  float hp1 = 0.f;

  const bool isProj = (jg < 3) && (wave >= 8);
  const int pv = jg * 16 + flr;
  const float fbv = (isProj && pv < kV) ? fc2b[pv] : 0.f;

  __syncthreads();

  const unsigned short* h0c = h0A; unsigned short* h0n_ = h0B;
  const unsigned short* h1c = h1A; unsigned short* h1n_ = h1B;
  const f32x4 zf = {0.f, 0.f, 0.f, 0.f};

  for (int t = 0; t < kSEQ; ++t) {
    // ---------- phase A ----------
    if (wave < 8) {           // T0: gi0|gh1, A = h1c, one 16-row m-tile
      const unsigned short* ap = h1c + (size_t)(m0 + wave * 16 + flr) * kH + q8;
      f32x4 acc[3] = {zf, zf, zf};
#pragma unroll 8
      for (int kf = 0; kf < 16; ++kf) {
        const int ko = kf * 32;
        const bf16x8 a = ld_h16(ap + ko);
#pragma unroll
        for (int g = 0; g < 3; ++g)
          acc[g] = __builtin_amdgcn_mfma_f32_16x16x32_bf16(
              a, *(const bf16x8*)&w[boffT0[g] + ko], acc[g], 0, 0, 0);
      }
#pragma unroll
      for (int g = 0; g < 3; ++g)
        *(f32x4*)&CsA[((g * 8 + wave) * 16 + flr) * 20 + quad * 4] = acc[g];
    } else {                  // T1: gh0, A = h0c
      const int mt = wave - 8;
      const unsigned short* ap = h0c + (size_t)(m0 + mt * 16 + flr) * kH + q8;
      f32x4 acc[3] = {zf, zf, zf};
#pragma unroll 8
      for (int kf = 0; kf < 16; ++kf) {
        const int ko = kf * 32;
        const bf16x8 a = ld_h16(ap + ko);
#pragma unroll
        for (int g = 0; g < 3; ++g)
          acc[g] = __builtin_amdgcn_mfma_f32_16x16x32_bf16(
              a, *(const bf16x8*)&w[boffT1[g] + ko], acc[g], 0, 0, 0);
      }
      if (flr < 8) {
#pragma unroll
        for (int g = 0; g < 3; ++g)
          *(f32x4*)&CsB[((g * 8 + mt) * 8 + flr) * 20 + quad * 4] = acc[g];
      }
    }
    __syncthreads();
    // ---------- gate L0 (1024 threads x 1 item) ----------
    {
      const float gir = CsA[((0 * 8 + gmt) * 16 + jl) * 20 + gml] + ((t == 0) ? bg0r : bbcr);
      const float giz = CsA[((1 * 8 + gmt) * 16 + jl) * 20 + gml] + ((t == 0) ? bg0z : bbcz);
      const float gin = CsA[((2 * 8 + gmt) * 16 + jl) * 20 + gml] + ((t == 0) ? bg0n : bbcn);
      const float ghr = CsB[((0 * 8 + gmt) * 8 + jl) * 20 + gml] + bh0r;
      const float ghz = CsB[((1 * 8 + gmt) * 8 + jl) * 20 + gml] + bh0z;
      const float ghn = CsB[((2 * 8 + gmt) * 8 + jl) * 20 + gml] + bh0n;
      const float r = sigm(gir + ghr);
      const float z = sigm(giz + ghz);
      const float n = tanhf(gin + r * ghn);
      const float h = (1.f - z) * n + z * hp0;
      hp0 = h;
      st_h2(h0n_ + (size_t)(m0 + gm) * kH + j, f2bf(h));
    }
    mg_barrier(bar, (unsigned)(2 * t + 1), mg, sub);
    // ---------- phase B ----------
    if (wave < 8) {           // gi1: A = h0n
      const unsigned short* ap = h0n_ + (size_t)(m0 + wave * 16 + flr) * kH + q8;
      f32x4 acc[3] = {zf, zf, zf};
#pragma unroll 8
      for (int kf = 0; kf < 16; ++kf) {
        const int ko = kf * 32;
        const bf16x8 a = ld_h16(ap + ko);
#pragma unroll
        for (int g = 0; g < 3; ++g)
          acc[g] = __builtin_amdgcn_mfma_f32_16x16x32_bf16(
              a, *(const bf16x8*)&w[boffB[g] + ko], acc[g], 0, 0, 0);
      }
      if (flr < 8) {
#pragma unroll
        for (int g = 0; g < 3; ++g)
          *(f32x4*)&CsB[((g * 8 + wave) * 8 + flr) * 20 + quad * 4] = acc[g];
      }
    } else if (isProj && t > 0) {   // out(t-1) = h1(t-1) @ fc2w^T
      const int mt = wave - 8;
      const unsigned short* ap = h1c + (size_t)(m0 + mt * 16 + flr) * kH + q8;
      const unsigned short* bp = fc2wb + (size_t)(jg * 16 + flr) * kH + q8;
      f32x4 pa = zf;
#pragma unroll 8
      for (int kf = 0; kf < 16; ++kf) {
        const int ko = kf * 32;
        pa = __builtin_amdgcn_mfma_f32_16x16x32_bf16(
            ld_h16(ap + ko), *(const bf16x8*)(bp + ko), pa, 0, 0, 0);
      }
      if (pv < kV) {
#pragma unroll
        for (int r = 0; r < 4; ++r)
          out[(size_t)(m0 + mt * 16 + quad * 4 + r) * (kSEQ * kV)
              + (size_t)(t - 1) * kV + pv] = pa[r] + fbv;
      }
    }
    __syncthreads();
    // ---------- gate L1 (1024 threads x 1 item) ----------
    {
      const float gir = CsB[((0 * 8 + gmt) * 8 + jl) * 20 + gml] + bi1r;
      const float giz = CsB[((1 * 8 + gmt) * 8 + jl) * 20 + gml] + bi1z;
      const float gin = CsB[((2 * 8 + gmt) * 8 + jl) * 20 + gml] + bi1n;
      const float ghr = CsA[((0 * 8 + gmt) * 16 + 8 + jl) * 20 + gml] + bh1r;
      const float ghz = CsA[((1 * 8 + gmt) * 16 + 8 + jl) * 20 + gml] + bh1z;
      const float ghn = CsA[((2 * 8 + gmt) * 16 + 8 + jl) * 20 + gml] + bh1n;
      const float r = sigm(gir + ghr);
      const float z = sigm(giz + ghz);
      const float n = tanhf(gin + r * ghn);
      const float h = (1.f - z) * n + z * hp1;
      hp1 = h;
      st_h2(h1n_ + (size_t)(m0 + gm) * kH + j, f2bf(h));
    }
    mg_barrier(bar, (unsigned)(2 * t + 2), mg, sub);
    {
      const unsigned short* tc;
      tc = h0c; h0c = h0n_; h0n_ = (unsigned short*)tc;
      tc = h1c; h1c = h1n_; h1n_ = (unsigned short*)tc;
    }
  }
  // ---------- tail projection: out[127] from final h1 ----------
  if (isProj) {
    const int mt = wave - 8;
    const unsigned short* ap = h1c + (size_t)(m0 + mt * 16 + flr) * kH + q8;
    const unsigned short* bp = fc2wb + (size_t)(jg * 16 + flr) * kH + q8;
    f32x4 pa = zf;
#pragma unroll 8
    for (int kf = 0; kf < 16; ++kf) {
      const int ko = kf * 32;
      pa = __builtin_amdgcn_mfma_f32_16x16x32_bf16(
          ld_h16(ap + ko), *(const bf16x8*)(bp + ko), pa, 0, 0, 0);
    }
    if (pv < kV) {
#pragma unroll
      for (int r = 0; r < 4; ++r)
        out[(size_t)(m0 + mt * 16 + quad * 4 + r) * (kSEQ * kV)
            + (size_t)(kSEQ - 1) * kV + pv] = pa[r] + fbv;
    }
  }
}

extern "C" void kernel_launch(void* const* d_in, const int* in_sizes, int n_in,
                              void* d_out, int out_size, void* d_ws, size_t ws_size,
                              hipStream_t stream) {
  const float* X    = (const float*)d_in[0];
  const float* eps  = (const float*)d_in[2];
  const float* e1w  = (const float*)d_in[3];  const float* e1b  = (const float*)d_in[4];
  const float* e2w  = (const float*)d_in[5];  const float* e2b  = (const float*)d_in[6];
  const float* e3w  = (const float*)d_in[7];  const float* e3b  = (const float*)d_in[8];
  const float* e41w = (const float*)d_in[9];  const float* e41b = (const float*)d_in[10];
  const float* e42w = (const float*)d_in[11]; const float* e42b = (const float*)d_in[12];
  const float* fc1w = (const float*)d_in[13]; const float* fc1b = (const float*)d_in[14];
  const float* fc2w = (const float*)d_in[15]; const float* fc2b = (const float*)d_in[16];
  const float* wih0 = (const float*)d_in[17]; const float* bih0 = (const float*)d_in[18];
  const float* whh0 = (const float*)d_in[19]; const float* bhh0 = (const float*)d_in[20];
  const float* wih1 = (const float*)d_in[21]; const float* bih1 = (const float*)d_in[22];
  const float* whh1 = (const float*)d_in[23]; const float* bhh1 = (const float*)d_in[24];
  float* out = (float*)d_out;

  float* ws = (float*)d_ws;
  float* eh1 = ws;
  unsigned short* Wcb   = (unsigned short*)(ws + 0);        // 786432 us
  unsigned short* whh0b = (unsigned short*)(ws + 393216);   // 786432 us
  unsigned short* fc2wb = (unsigned short*)(ws + 786432);   // 24576 us
  float* eh2 = ws + 1048576;
  unsigned short* wih1b = (unsigned short*)(ws + 1048576);  // 786432 us
  unsigned short* whh1b = (unsigned short*)(ws + 1441792);  // 786432 us
  float* eh3 = ws + 1572864;
  float* latg = ws + 1835008;                               // 262144 f
  unsigned short* h0a = (unsigned short*)(ws + 2097152);
  unsigned short* h0b = (unsigned short*)(ws + 2228224);
  unsigned short* h1a = (unsigned short*)(ws + 2359296);
  unsigned short* h1b = (unsigned short*)(ws + 2490368);
  float* mu  = ws + 2621440;
  float* lv  = ws + 2654208;
  float* enc = ws + 2686976;
  float* bc  = ws + 2719744;
  float* g0  = ws + 2721280;
  unsigned* bar = (unsigned*)(ws + 2723840);                // 1024 u32

  const size_t dec_elems = (size_t)kB * kSEQ * kV;

  // ---- encoder ----
  gemm_bias<true ><<<dim3(32, 8), 256, 0, stream>>>(X,   e1w, e1b, eh1, kB, 2048, 4096);
  gemm_bias<true ><<<dim3(16, 8), 256, 0, stream>>>(eh1, e2w, e2b, eh2, kB, 1024, 2048);
  gemm_bias<true ><<<dim3( 8, 8), 256, 0, stream>>>(eh2, e3w, e3b, eh3, kB,  512, 1024);
  gemm_bias<false><<<dim3( 1, 8), 256, 0, stream>>>(eh3, e41w, e41b, mu, kB,   64,  512);
  gemm_bias<false><<<dim3( 1, 8), 256, 0, stream>>>(eh3, e42w, e42b, lv, kB,   64,  512);
  hipMemsetAsync(out + dec_elems, 0, sizeof(float), stream);
  enc_kld<<<128, 256, 0, stream>>>(mu, lv, eps, enc, out + dec_elems);
  gemm_bias<false><<<dim3(8, 8), 256, 0, stream>>>(enc, fc1w, fc1b, latg, kB, kH, kENC);

  // ---- weight prep (bf16) + barrier init ----
  prep_comb<<<3072, 256, 0, stream>>>(wih0, bih0, fc2w, fc2b, Wcb, bc, g0);
  conv_bf16<<<3072, 256, 0, stream>>>(whh0, whh0b, 1536 * kH);
  conv_bf16<<<3072, 256, 0, stream>>>(wih1, wih1b, 1536 * kH);
  conv_bf16<<<3072, 256, 0, stream>>>(whh1, whh1b, 1536 * kH);
  conv_fc2w_pad<<<96, 256, 0, stream>>>(fc2w, fc2wb);
  conv_bf16<<<1024, 256, 0, stream>>>(latg, h0a, kB * kH);
  hipMemsetAsync(h1a, 0, (size_t)kB * kH * sizeof(unsigned short), stream);
  hipMemsetAsync(bar, 0, 4096, stream);

  // ---- persistent MFMA GRU decoder ----
  hipFuncSetAttribute((const void*)gru_mfma,
                      hipFuncAttributeMaxDynamicSharedMemorySize, kLdsBytes);
  void* args[] = { (void*)&Wcb, (void*)&whh0b, (void*)&wih1b, (void*)&whh1b,
                   (void*)&fc2wb, (void*)&bc, (void*)&g0, (void*)&bhh0,
                   (void*)&bih1, (void*)&bhh1, (void*)&fc2b, (void*)&latg,
                   (void*)&h0a, (void*)&h0b, (void*)&h1a, (void*)&h1b,
                   (void*)&out, (void*)&bar };
  hipLaunchCooperativeKernel((void*)gru_mfma, dim3(256), dim3(1024), args,
                             kLdsBytes, stream);
}